// Round 8
// baseline (882.379 us; speedup 1.0000x reference)
//
#include <hip/hip_runtime.h>
#include <hip/hip_fp16.h>

// SpectralAttention: B=4, S=1024, E=1024, H=16, HD=64.
// Identity: real(ifft2(F*exp(i*phi))) == ifft2(F * cos(phi)) for real scores
// => real spectral gain, Hermitian half-spectrum (v=0..512).
//
// Round-13:
//  - k56 REVERTED to round-11 (ILP-2 regressed: LDS-capped occupancy).
//  - k0b: one-shot dtype conversion (x,Wq,Wk,Wv -> bf16; biases -> f32);
//    k1 is now a pure-bf16 GEMM (no per-tile f32->bf16 conversion).
//    Converted buffers live in the dead [16M,32M) stripe of the Ct overlay
//    => B_NEED unchanged (~169 MB).
//  - k4: ILP-4 (4 v-rows/wave, shared twiddles, zero LDS).
//
// Big layout (~169 MiB): Ct-all 128.25M (overlays Qt 8M | Kt 8M | xb 8M |
//   Wqb/Wkb/Wvb 6M | biases) | Vt | ctx | Qhat | Khat | flags

typedef __attribute__((ext_vector_type(8))) short short8;
typedef __attribute__((ext_vector_type(8))) _Float16 half8;
typedef __attribute__((ext_vector_type(4))) float f32x4;

#define PITCH 40    // k7 staging pitch (BK=32)
#define PITCH1 72   // k1 staging pitch (BK=64)

__device__ __forceinline__ float bf2f(short v) {
  return __uint_as_float(((unsigned)(unsigned short)v) << 16);
}
__device__ __forceinline__ short f2bf(float f) {
  unsigned u = __float_as_uint(f);
  u += 0x7FFFu + ((u >> 16) & 1u);  // RNE
  return (short)(u >> 16);
}

__device__ __forceinline__ short8 ld8(const void* p, size_t idx, int isf32) {
  short8 r;
  if (isf32) {
    const float* f = (const float*)p + idx;
    float4 a = *(const float4*)f;
    float4 b = *(const float4*)(f + 4);
    r[0] = f2bf(a.x); r[1] = f2bf(a.y); r[2] = f2bf(a.z); r[3] = f2bf(a.w);
    r[4] = f2bf(b.x); r[5] = f2bf(b.y); r[6] = f2bf(b.z); r[7] = f2bf(b.w);
  } else {
    r = *(const short8*)((const short*)p + idx);
  }
  return r;
}
__device__ __forceinline__ float ldf(const void* p, int idx, int isf32) {
  return isf32 ? ((const float*)p)[idx] : bf2f(((const short*)p)[idx]);
}

__device__ __forceinline__ float2 cmul(float2 a, float2 b) {
  return make_float2(a.x * b.x - a.y * b.y, a.x * b.y + a.y * b.x);
}
__device__ __forceinline__ float2 cmulc(float2 a, float2 b) {  // a * conj(b)
  return make_float2(a.x * b.x + a.y * b.y, a.y * b.x - a.x * b.y);
}
__device__ __forceinline__ float2 cadd(float2 a, float2 b) {
  return make_float2(a.x + b.x, a.y + b.y);
}
__device__ __forceinline__ float2 csub(float2 a, float2 b) {
  return make_float2(a.x - b.x, a.y - b.y);
}

// ================== wave-register 1024-pt FFT (16 in-reg x 64 cross-lane) ==
// Layout: lane l holds z[l + 64*j], j=0..15 (n1 = lane, n2 = reg).
// Forward DIF output: (lane l, reg r) holds F[bitrev4(r) + 16*bitrev6(l)].
// wfft1024_dif<-1> = true DFT (W^-), <+1> = unnormalized inverse (W^+).
// wfft1024_inv4 = stage-mirror of dif<-1>, 4 rows per wave.

template <int SGN>
__device__ __forceinline__ void dft16_dif(float2* x) {
  const float C16[8] = {1.f, 0.92387953f, 0.70710678f, 0.38268343f,
                        0.f, -0.38268343f, -0.70710678f, -0.92387953f};
  const float S16[8] = {0.f, 0.38268343f, 0.70710678f, 0.92387953f,
                        1.f, 0.92387953f, 0.70710678f, 0.38268343f};
#pragma unroll
  for (int h = 8; h >= 1; h >>= 1)
#pragma unroll
    for (int b = 0; b < 16; b += 2 * h)
#pragma unroll
      for (int i = 0; i < h; ++i) {
        const int e = i * (8 / h);
        float2 u = x[b + i], v = x[b + i + h];
        x[b + i] = cadd(u, v);
        float2 d = csub(u, v);
        float2 w = make_float2(C16[e], SGN > 0 ? S16[e] : -S16[e]);
        x[b + i + h] = (e == 0) ? d : cmul(d, w);
      }
}

__device__ __forceinline__ void dit16_inv(float2* x) {
  const float C16[8] = {1.f, 0.92387953f, 0.70710678f, 0.38268343f,
                        0.f, -0.38268343f, -0.70710678f, -0.92387953f};
  const float S16[8] = {0.f, 0.38268343f, 0.70710678f, 0.92387953f,
                        1.f, 0.92387953f, 0.70710678f, 0.38268343f};
#pragma unroll
  for (int h = 1; h <= 8; h <<= 1)
#pragma unroll
    for (int b = 0; b < 16; b += 2 * h)
#pragma unroll
      for (int i = 0; i < h; ++i) {
        const int e = i * (8 / h);
        float2 w = make_float2(C16[e], -S16[e]);
        float2 u = x[b + i];
        float2 vh = (e == 0) ? x[b + i + h] : cmulc(x[b + i + h], w);
        x[b + i] = cadd(u, vh);
        x[b + i + h] = csub(u, vh);
      }
}

template <int SGN>
__device__ __forceinline__ void midtw(float2* x, int lane) {
  const int rho[16] = {0, 8, 4, 12, 2, 10, 6, 14, 1, 9, 5, 13, 3, 11, 7, 15};
  float s, c;
  __sincosf((float)lane * 0.00613592315f, &s, &c);  // 2pi/1024
  float2 w = make_float2(c, SGN > 0 ? s : -s);
  float2 run = w;
  x[8] = cmul(x[8], run);
#pragma unroll
  for (int e = 2; e < 16; ++e) {
    run = cmul(run, w);
    x[rho[e]] = cmul(x[rho[e]], run);
  }
}

template <int SGN>
__device__ __forceinline__ void xlane_dif(float2* x, int lane) {
#pragma unroll
  for (int h = 32; h >= 1; h >>= 1) {
    const int e = (lane & (h - 1)) * (32 / h);
    float s, c;
    __sincosf((float)e * 0.09817477042f, &s, &c);  // 2pi/64
    float2 w = make_float2(c, SGN > 0 ? s : -s);
    const bool hi = (lane & h) != 0;
#pragma unroll
    for (int r = 0; r < 16; ++r) {
      float2 t = x[r];
      float2 p;
      p.x = __shfl_xor(t.x, h, 64);
      p.y = __shfl_xor(t.y, h, 64);
      x[r] = hi ? cmul(csub(p, t), w) : cadd(t, p);
    }
  }
}

template <int SGN>
__device__ __forceinline__ void wfft1024_dif(float2* x, int lane) {
  dft16_dif<SGN>(x);
  midtw<SGN>(x, lane);
  xlane_dif<SGN>(x, lane);
}

// -------- paired (two-row) forward variant (kA Q-side) ----
template <int SGN>
__device__ __forceinline__ void midtw2(float2* x, float2* y, int lane) {
  const int rho[16] = {0, 8, 4, 12, 2, 10, 6, 14, 1, 9, 5, 13, 3, 11, 7, 15};
  float s, c;
  __sincosf((float)lane * 0.00613592315f, &s, &c);
  float2 w = make_float2(c, SGN > 0 ? s : -s);
  float2 run = w;
  x[8] = cmul(x[8], run);
  y[8] = cmul(y[8], run);
#pragma unroll
  for (int e = 2; e < 16; ++e) {
    run = cmul(run, w);
    x[rho[e]] = cmul(x[rho[e]], run);
    y[rho[e]] = cmul(y[rho[e]], run);
  }
}

template <int SGN>
__device__ __forceinline__ void xlane_dif2(float2* x, float2* y, int lane) {
#pragma unroll
  for (int h = 32; h >= 1; h >>= 1) {
    const int e = (lane & (h - 1)) * (32 / h);
    float s, c;
    __sincosf((float)e * 0.09817477042f, &s, &c);
    float2 w = make_float2(c, SGN > 0 ? s : -s);
    const bool hi = (lane & h) != 0;
#pragma unroll
    for (int r = 0; r < 16; ++r) {
      float2 t = x[r];
      float2 p;
      p.x = __shfl_xor(t.x, h, 64);
      p.y = __shfl_xor(t.y, h, 64);
      x[r] = hi ? cmul(csub(p, t), w) : cadd(t, p);
    }
#pragma unroll
    for (int r = 0; r < 16; ++r) {
      float2 t = y[r];
      float2 p;
      p.x = __shfl_xor(t.x, h, 64);
      p.y = __shfl_xor(t.y, h, 64);
      y[r] = hi ? cmul(csub(p, t), w) : cadd(t, p);
    }
  }
}

template <int SGN>
__device__ __forceinline__ void wfft1024_dif2(float2* x, float2* y, int lane) {
  dft16_dif<SGN>(x);
  dft16_dif<SGN>(y);
  midtw2<SGN>(x, y, lane);
  xlane_dif2<SGN>(x, y, lane);
}

// -------- 4-row inverse (k4): shared twiddles, 4x ILP per stage ----
__device__ __forceinline__ void xlane_dit_inv4(float2* x0, float2* x1,
                                               float2* x2, float2* x3, int lane) {
#pragma unroll
  for (int h = 1; h <= 32; h <<= 1) {
    const int e = (lane & (h - 1)) * (32 / h);
    float s, c;
    __sincosf((float)e * 0.09817477042f, &s, &c);
    float2 w = make_float2(c, -s);
    const bool hi = (lane & h) != 0;
#pragma unroll
    for (int r = 0; r < 16; ++r) {
      float2 t = x0[r];
      if (hi) t = cmulc(t, w);
      float2 p;
      p.x = __shfl_xor(t.x, h, 64);
      p.y = __shfl_xor(t.y, h, 64);
      x0[r] = hi ? csub(p, t) : cadd(t, p);
    }
#pragma unroll
    for (int r = 0; r < 16; ++r) {
      float2 t = x1[r];
      if (hi) t = cmulc(t, w);
      float2 p;
      p.x = __shfl_xor(t.x, h, 64);
      p.y = __shfl_xor(t.y, h, 64);
      x1[r] = hi ? csub(p, t) : cadd(t, p);
    }
#pragma unroll
    for (int r = 0; r < 16; ++r) {
      float2 t = x2[r];
      if (hi) t = cmulc(t, w);
      float2 p;
      p.x = __shfl_xor(t.x, h, 64);
      p.y = __shfl_xor(t.y, h, 64);
      x2[r] = hi ? csub(p, t) : cadd(t, p);
    }
#pragma unroll
    for (int r = 0; r < 16; ++r) {
      float2 t = x3[r];
      if (hi) t = cmulc(t, w);
      float2 p;
      p.x = __shfl_xor(t.x, h, 64);
      p.y = __shfl_xor(t.y, h, 64);
      x3[r] = hi ? csub(p, t) : cadd(t, p);
    }
  }
}

__device__ __forceinline__ void midtw_inv4(float2* x0, float2* x1,
                                           float2* x2, float2* x3, int lane) {
  const int rho[16] = {0, 8, 4, 12, 2, 10, 6, 14, 1, 9, 5, 13, 3, 11, 7, 15};
  float s, c;
  __sincosf((float)lane * 0.00613592315f, &s, &c);
  float2 w = make_float2(c, -s);
  float2 run = w;
  x0[8] = cmulc(x0[8], run);
  x1[8] = cmulc(x1[8], run);
  x2[8] = cmulc(x2[8], run);
  x3[8] = cmulc(x3[8], run);
#pragma unroll
  for (int e = 2; e < 16; ++e) {
    run = cmul(run, w);
    x0[rho[e]] = cmulc(x0[rho[e]], run);
    x1[rho[e]] = cmulc(x1[rho[e]], run);
    x2[rho[e]] = cmulc(x2[rho[e]], run);
    x3[rho[e]] = cmulc(x3[rho[e]], run);
  }
}

__device__ __forceinline__ void wfft1024_inv4(float2* x0, float2* x1,
                                              float2* x2, float2* x3, int lane) {
  xlane_dit_inv4(x0, x1, x2, x3, lane);
  midtw_inv4(x0, x1, x2, x3, lane);
  dit16_inv(x0);
  dit16_inv(x1);
  dit16_inv(x2);
  dit16_inv(x3);
}

// spectral gain; 1/N^2 folded in. alpha==1: cos(atan t) == rsqrt(1+t^2).
__device__ __forceinline__ float gainw(float re, float im, float alpha, bool a1) {
  float mag2 = re * re + im * im;
  float t = 0.5f * __logf(mag2 + 1e-20f);
  if (a1) return __builtin_amdgcn_rsqf(fmaf(t, t, 1.0f)) * (1.0f / 1048576.0f);
  return __cosf(alpha * atanf(t)) * (1.0f / 1048576.0f);
}

// ------------------------------------------------- k0: dtype detect + alpha
__global__ void k0_detect(const unsigned* __restrict__ q,
                          const void* __restrict__ alphap, int* __restrict__ flags) {
  __shared__ float smax[256];
  __shared__ int szero[256];
  int t = threadIdx.x;
  float mx = 0.f; int zc = 0;
  for (int i = t; i < 16384; i += 256) {
    unsigned w = q[i];
    unsigned lo = w & 0xFFFFu;
    float v = fabsf(__uint_as_float(lo << 16));
    if (!(v <= 1e30f)) v = 1e30f;
    mx = fmaxf(mx, v);
    zc += (lo == 0u);
  }
  smax[t] = mx; szero[t] = zc;
  __syncthreads();
  for (int s = 128; s > 0; s >>= 1) {
    if (t < s) { smax[t] = fmaxf(smax[t], smax[t + s]); szero[t] += szero[t + s]; }
    __syncthreads();
  }
  if (t == 0) {
    int isf32 = (smax[0] > 100.f) || (szero[0] > 12288);
    flags[0] = isf32;
    float alpha = isf32 ? *(const float*)alphap : bf2f(*(const short*)alphap);
    ((float*)flags)[1] = alpha;
  }
}

// ------------------------------------------------- k0b: one-shot dtype convert
// x, Wq, Wk, Wv -> bf16; biases -> f32. Chunks of 8 elems.
// x: 524288 chunks | Wq/Wk/Wv: 131072 each | biases: 3*128 chunks.
__global__ __launch_bounds__(256) void k0b_convert(
    const void* __restrict__ x,
    const void* __restrict__ Wq, const void* __restrict__ bq,
    const void* __restrict__ Wk, const void* __restrict__ bk,
    const void* __restrict__ Wv, const void* __restrict__ bv,
    short* __restrict__ xb, short* __restrict__ Wqb,
    short* __restrict__ Wkb, short* __restrict__ Wvb,
    float* __restrict__ bqf, float* __restrict__ bkf, float* __restrict__ bvf,
    const int* __restrict__ flags)
{
  const int isf32 = flags[0];
  const int gid = blockIdx.x * 256 + threadIdx.x;
  if (gid < 524288) {
    *(short8*)&xb[(size_t)gid * 8] = ld8(x, (size_t)gid * 8, isf32);
  } else if (gid < 524288 + 3 * 131072) {
    int r = gid - 524288;
    int wsel = r / 131072;
    size_t off = (size_t)(r % 131072) * 8;
    const void* W = (wsel == 0) ? Wq : (wsel == 1) ? Wk : Wv;
    short* O = (wsel == 0) ? Wqb : (wsel == 1) ? Wkb : Wvb;
    *(short8*)&O[off] = ld8(W, off, isf32);
  } else {
    int r = gid - (524288 + 3 * 131072);
    if (r < 3 * 128) {
      int bsel = r / 128, off = (r % 128) * 8;
      const void* B = (bsel == 0) ? bq : (bsel == 1) ? bk : bv;
      float* O = (bsel == 0) ? bqf : (bsel == 1) ? bkf : bvf;
#pragma unroll
      for (int i = 0; i < 8; ++i) O[off + i] = ldf(B, off + i, isf32);
    }
  }
}

// ------------------------------------------------- k1: QKV projection (XCD-swizzled)
// Pure bf16 (pre-converted inputs). BK=64. Outputs transposed: O[plane][d][s].
__global__ __launch_bounds__(256) void k1_qkv(
    const short* __restrict__ xb,
    const short* __restrict__ Wqb, const float* __restrict__ bqf,
    const short* __restrict__ Wkb, const float* __restrict__ bkf,
    const short* __restrict__ Wvb, const float* __restrict__ bvf,
    short* __restrict__ Qt, short* __restrict__ Kt, short* __restrict__ Vt)
{
  __shared__ __align__(16) char smem[128 * PITCH1 * 2 * 2];  // 36864 B
  short* As = (short*)smem;
  short* Bs = As + 128 * PITCH1;
  short* Ct = (short*)smem;  // epilogue overlay (34816 B)
  const int t = threadIdx.x;
  const int lb = blockIdx.x;
  const int m0 = ((lb & 7) * 4 + ((lb >> 3) & 3)) * 128;
  const int n0 = (lb >> 5) * 128;
  const int which = blockIdx.y;
  const short* __restrict__ W = (which == 0) ? Wqb : (which == 1) ? Wkb : Wvb;
  const float* __restrict__ bias = (which == 0) ? bqf : (which == 1) ? bkf : bvf;
  const int lane = t & 63, wvi = t >> 6;
  const int wr = wvi >> 1, wc = wvi & 1;
  const int lm = lane & 15, lq = lane >> 4;
  f32x4 acc[4][4] = {};

  for (int k0 = 0; k0 < 1024; k0 += 64) {
    __syncthreads();
#pragma unroll
    for (int i = 0; i < 4; ++i) {
      int l = t + i * 256;
      int row = l >> 3, kk = (l & 7) << 3;
      *(short8*)&As[row * PITCH1 + kk] = *(const short8*)&xb[(size_t)(m0 + row) * 1024 + k0 + kk];
      *(short8*)&Bs[row * PITCH1 + kk] = *(const short8*)&W[(size_t)(n0 + row) * 1024 + k0 + kk];
    }
    __syncthreads();
#pragma unroll
    for (int kh = 0; kh < 2; ++kh) {
      short8 af[4], bf[4];
#pragma unroll
      for (int a = 0; a < 4; ++a)
        af[a] = *(const short8*)&As[(wr * 64 + a * 16 + lm) * PITCH1 + kh * 32 + lq * 8];
#pragma unroll
      for (int b = 0; b < 4; ++b)
        bf[b] = *(const short8*)&Bs[(wc * 64 + b * 16 + lm) * PITCH1 + kh * 32 + lq * 8];
#pragma unroll
      for (int a = 0; a < 4; ++a)
#pragma unroll
        for (int b = 0; b < 4; ++b)
          acc[a][b] = __builtin_amdgcn_mfma_f32_16x16x32_bf16(af[a], bf[b], acc[a][b], 0, 0, 0);
    }
  }

  __syncthreads();
#pragma unroll
  for (int a = 0; a < 4; ++a)
#pragma unroll
    for (int b = 0; b < 4; ++b) {
      int col = wc * 64 + b * 16 + lm;
      float bv_ = bias[n0 + col];
#pragma unroll
      for (int r = 0; r < 4; ++r) {
        int row = wr * 64 + a * 16 + lq * 4 + r;
        Ct[row * 136 + col] = f2bf(acc[a][b][r] + bv_);
      }
    }
  __syncthreads();

  short* __restrict__ O = (which == 0) ? Qt : (which == 1) ? Kt : Vt;
#pragma unroll
  for (int j = 0; j < 8; ++j) {
    int id = t + j * 256;
    int d128 = id & 127, sg = (id >> 7) * 8;
    short vals[8];
#pragma unroll
    for (int i = 0; i < 8; ++i) vals[i] = Ct[(sg + i) * 136 + d128];
    int col = n0 + d128;
    int h = col >> 6, d = col & 63;
    int bb = m0 >> 10, sbase = (m0 & 1023) + sg;
    *(short8*)&O[(((size_t)(bb * 16 + h)) << 16) + ((size_t)d << 10) + sbase] = *(short8*)vals;
  }
}

// ------------------------------------------------- kA: column FFTs of Q and K
// ONE dispatch, all 64 planes: grid (32, 64), 128 threads (2 waves).
__global__ __launch_bounds__(128) void kA_qkfft(
    const short* __restrict__ Qt, const short* __restrict__ Kt,
    __half2* __restrict__ Qhat, __half2* __restrict__ Khat)
{
  __shared__ float2 sbuf[2][1024];
  const int lane = threadIdx.x & 63, w = threadIdx.x >> 6;
  const int z = blockIdx.y;
  const int bx = blockIdx.x;
  if (bx < 16) {
    const short* qp = Qt + ((size_t)z << 16);
    const int d0 = bx * 4 + w * 2;
    float2 x[16], y[16];
#pragma unroll
    for (int j = 0; j < 16; ++j) {
      x[j] = make_float2(0.125f * bf2f(qp[(d0 << 10) + lane + 64 * j]), 0.f);
      y[j] = make_float2(0.125f * bf2f(qp[((d0 + 1) << 10) + lane + 64 * j]), 0.f);
    }
    wfft1024_dif2<-1>(x, y, lane);
    __half2* o0 = Qhat + (((size_t)(z * 64 + d0)) << 10);
    __half2* o1 = o0 + 1024;
#pragma unroll
    for (int r = 0; r < 16; ++r) {
      o0[lane + 64 * r] = __float22half2_rn(x[r]);
      o1[lane + 64 * r] = __float22half2_rn(y[r]);
    }
  } else {
    const short* kp = Kt + ((size_t)z << 16);
    const int p = (bx - 16) * 2 + w;
    const int d0 = 2 * p;
    float2 x[16];
#pragma unroll
    for (int j = 0; j < 16; ++j)
      x[j] = make_float2(bf2f(kp[(d0 << 10) + lane + 64 * j]),
                         bf2f(kp[((d0 + 1) << 10) + lane + 64 * j]));
    wfft1024_dif<-1>(x, lane);
    const int rho[16] = {0, 8, 4, 12, 2, 10, 6, 14, 1, 9, 5, 13, 3, 11, 7, 15};
    const int bl6 = ((lane & 1) << 5) | ((lane & 2) << 3) | ((lane & 4) << 1) |
                    ((lane & 8) >> 1) | ((lane & 16) >> 3) | ((lane & 32) >> 5);
    float2* buf = sbuf[w];
#pragma unroll
    for (int r = 0; r < 16; ++r) buf[rho[r] + 16 * bl6] = x[r];
    __half2* o0 = Khat + (size_t)(z * 64 + d0) * 520;
    __half2* o1 = o0 + 520;
#pragma unroll 1
    for (int jj = 0; jj < 9; ++jj) {
      int v = lane + 64 * jj;
      if (v <= 512) {
        float2 A = buf[v], B = buf[(1024 - v) & 1023];
        // K1 = (Z + conj(Z~))/2 ; K2 = (Z - conj(Z~))/(2i)
        o0[v] = __float22half2_rn(make_float2((A.x + B.x) * 0.5f, (A.y - B.y) * 0.5f));
        o1[v] = __float22half2_rn(make_float2((A.y + B.y) * 0.5f, (B.x - A.x) * 0.5f));
      }
    }
  }
}

// ------------------------------------------------- kB: F2D = Khat x Qhat^T + gain
// C[v][u-slot], M=64 (v), N=128 (u), K=64 (d). fp16 MFMA, f32 accum.
__global__ __launch_bounds__(256) void kB_specmm(
    const __half2* __restrict__ Qhat, const __half2* __restrict__ Khat,
    __half2* __restrict__ Ct, const int* __restrict__ flags, int bh0)
{
  __shared__ unsigned short Are[64][72], Aim[64][72], Bre[128][72], Bim[128][72];
  const int t = threadIdx.x;
  const int u0 = blockIdx.x * 128;
  const int v0 = blockIdx.y * 64;
  const int zl = blockIdx.z;
  const int z = bh0 + zl;
  const float alpha = ((const float*)flags)[1];
  const bool a1 = (alpha == 1.0f);
  {
    const int d = t >> 2;
    const ushort2* src = (const ushort2*)(Khat + (size_t)(z * 64 + d) * 520);
    int vb = (t & 3) * 16;
#pragma unroll
    for (int j = 0; j < 16; ++j) {
      int v = v0 + vb + j;
      if (v > 519) v = 519;
      ushort2 e = src[v];
      int row = vb + j;
      int dc = d ^ (((row >> 4) & 3) << 4);  // bank-spread swizzle
      Are[row][dc] = e.x;
      Aim[row][dc] = e.y;
    }
    const ushort2* srcb = (const ushort2*)(Qhat + (((size_t)(z * 64 + d)) << 10) + u0);
    int ub = (t & 3) * 32;
#pragma unroll
    for (int j = 0; j < 32; ++j) {
      ushort2 e = srcb[ub + j];
      int row = ub + j;
      int dc = d ^ (((row >> 5) & 3) << 4);
      Bre[row][dc] = e.x;
      Bim[row][dc] = e.y;
    }
  }
  __syncthreads();

  const int lane = t & 63, wc = t >> 6;
  const int lm = lane & 15, lq = lane >> 4;
  f32x4 cre[4][2] = {}, cim[4][2] = {};
#pragma unroll
  for (int ks = 0; ks < 2; ++ks) {
    half8 ar[4], ai[4], aiN[4], br[2], bi[2];
#pragma unroll
    for (int a = 0; a < 4; ++a) {
      int dc = (ks * 32 + lq * 8) ^ ((a & 3) << 4);
      ar[a] = *(const half8*)&Are[a * 16 + lm][dc];
      ai[a] = *(const half8*)&Aim[a * 16 + lm][dc];
      int4 tm = *(int4*)&ai[a];
      tm.x ^= 0x80008000; tm.y ^= 0x80008000; tm.z ^= 0x80008000; tm.w ^= 0x80008000;
      aiN[a] = *(half8*)&tm;
    }
#pragma unroll
    for (int n = 0; n < 2; ++n) {
      int dc = (ks * 32 + lq * 8) ^ ((wc & 3) << 4);
      br[n] = *(const half8*)&Bre[wc * 32 + n * 16 + lm][dc];
      bi[n] = *(const half8*)&Bim[wc * 32 + n * 16 + lm][dc];
    }
#pragma unroll
    for (int a = 0; a < 4; ++a)
#pragma unroll
      for (int n = 0; n < 2; ++n) {
        cre[a][n] = __builtin_amdgcn_mfma_f32_16x16x32_f16(ar[a], br[n], cre[a][n], 0, 0, 0);
        cre[a][n] = __builtin_amdgcn_mfma_f32_16x16x32_f16(aiN[a], bi[n], cre[a][n], 0, 0, 0);
        cim[a][n] = __builtin_amdgcn_mfma_f32_16x16x32_f16(ar[a], bi[n], cim[a][n], 0, 0, 0);
        cim[a][n] = __builtin_amdgcn_mfma_f32_16x16x32_f16(ai[a], br[n], cim[a][n], 0, 0, 0);
      }
  }

  __half2* outp = Ct + (size_t)zl * 513 * 1024 + u0 + wc * 32;
#pragma unroll
  for (int a = 0; a < 4; ++a)
#pragma unroll
    for (int r = 0; r < 4; ++r) {
      int v = v0 + a * 16 + lq * 4 + r;
      if (v < 513) {
#pragma unroll
        for (int n = 0; n < 2; ++n) {
          float re = cre[a][n][r], im = cim[a][n][r];
          float wf = gainw(re, im, alpha, a1);
          outp[(size_t)v * 1024 + n * 16 + lm] =
              __float22half2_rn(make_float2(re * wf, im * wf));
        }
      }
    }
}

// ------------------------------------------------- k4: inverse u-FFT (in place)
// Reads F~[v][u-slot] (scrambled-u), writes G[v][q] natural. FOUR rows/wave.
__global__ __launch_bounds__(256) void k4_invfft(__half2* __restrict__ Ct)
{
  const int lane = threadIdx.x & 63;
  const int w = threadIdx.x >> 6;
  const int gv0 = blockIdx.x * 16 + w * 4;
  if (gv0 > 512) return;
  const int nv = (513 - gv0 < 4) ? (513 - gv0) : 4;
  __half2* __restrict__ row0 = Ct + (size_t)blockIdx.y * 513 * 1024 + ((size_t)gv0 << 10);
  float2 x0[16], x1[16], x2[16], x3[16];
#pragma unroll
  for (int j = 0; j < 16; ++j) x0[j] = __half22float2(row0[lane + 64 * j]);
  if (nv > 1) {
#pragma unroll
    for (int j = 0; j < 16; ++j) x1[j] = __half22float2(row0[1024 + lane + 64 * j]);
  } else {
#pragma unroll
    for (int j = 0; j < 16; ++j) x1[j] = make_float2(0.f, 0.f);
  }
  if (nv > 2) {
#pragma unroll
    for (int j = 0; j < 16; ++j) x2[j] = __half22float2(row0[2048 + lane + 64 * j]);
  } else {
#pragma unroll
    for (int j = 0; j < 16; ++j) x2[j] = make_float2(0.f, 0.f);
  }
  if (nv > 3) {
#pragma unroll
    for (int j = 0; j < 16; ++j) x3[j] = __half22float2(row0[3072 + lane + 64 * j]);
  } else {
#pragma unroll
    for (int j = 0; j < 16; ++j) x3[j] = make_float2(0.f, 0.f);
  }

  wfft1024_inv4(x0, x1, x2, x3, lane);

#pragma unroll
  for (int j = 0; j < 16; ++j) row0[lane + 64 * j] = __float22half2_rn(x0[j]);
  if (nv > 1) {
#pragma unroll
    for (int j = 0; j < 16; ++j) row0[1024 + lane + 64 * j] = __float22half2_rn(x1[j]);
  }
  if (nv > 2) {
#pragma unroll
    for (int j = 0; j < 16; ++j) row0[2048 + lane + 64 * j] = __float22half2_rn(x2[j]);
  }
  if (nv > 3) {
#pragma unroll
    for (int j = 0; j < 16; ++j) row0[3072 + lane + 64 * j] = __float22half2_rn(x3[j]);
  }
}

// ------------------------------------------------- k56: inverse row FFT + softmax + PV
// 512 threads / 8 waves, single round: wave w owns p-pair w (rows 2w, 2w+1).
// Gbuf pitch 2064 B (2-way staging); P scatter via rho-involution reorder
// -> 2x ds_write_b128/row.  [round-11 version — proven 186 us]
__global__ __launch_bounds__(512) void k56_softmax_av(
    const __half2* __restrict__ Ct, const short* __restrict__ Vt,
    short* __restrict__ ctx, int bh0)
{
  __shared__ __align__(16) char GP[33280];
  const int tid = threadIdx.x;
  const int q0 = blockIdx.x * 16, z = blockIdx.y;
  const int lane = tid & 63, w = tid >> 6;  // w = 0..7
  const int lm = lane & 15, lq = lane >> 4;
  const __half2* __restrict__ in = Ct + (size_t)z * 513 * 1024;
#define GROW(m) ((__half2*)(GP + (m) * 2064))
  for (int id = tid; id < 2052; id += 512) {
    int v = id >> 2, qq = (id & 3) * 4;
    int4 o = *(const int4*)&in[(size_t)v * 1024 + q0 + qq];
    __half2* op = (__half2*)&o;
#pragma unroll
    for (int i = 0; i < 4; ++i) GROW(qq + i)[v] = op[i];
  }
  short* P = (short*)GP;  // row m at m*1040 shorts
  const int bl6 = ((lane & 1) << 5) | ((lane & 2) << 3) | ((lane & 4) << 1) |
                  ((lane & 8) >> 1) | ((lane & 16) >> 3) | ((lane & 32) >> 5);
  __syncthreads();  // Gbuf ready

  const int p = w;
  const __half2* g1 = GROW(2 * p);
  const __half2* g2 = GROW(2 * p + 1);
  float2 x[16];
#pragma unroll
  for (int j = 0; j < 16; ++j) {
    int v = lane + 64 * j;
    float2 a, b;
    if (v <= 512) {
      a = __half22float2(g1[v]);
      b = __half22float2(g2[v]);
    } else {
      int v2 = 1024 - v;
      float2 aa = __half22float2(g1[v2]), bb = __half22float2(g2[v2]);
      a = make_float2(aa.x, -aa.y);
      b = make_float2(bb.x, -bb.y);
    }
    x[j] = make_float2(a.x - b.y, a.y + b.x);
  }

  wfft1024_dif<1>(x, lane);  // sum_v z W^{+vk}: Re = row 2p, Im = row 2p+1

  float m1 = -3.4e38f, m2 = -3.4e38f;
#pragma unroll
  for (int j = 0; j < 16; ++j) { m1 = fmaxf(m1, x[j].x); m2 = fmaxf(m2, x[j].y); }
#pragma unroll
  for (int s = 32; s > 0; s >>= 1) {
    m1 = fmaxf(m1, __shfl_xor(m1, s, 64));
    m2 = fmaxf(m2, __shfl_xor(m2, s, 64));
  }
  float s1 = 0.f, s2 = 0.f;
#pragma unroll
  for (int j = 0; j < 16; ++j) {
    float e1 = __expf(x[j].x - m1), e2 = __expf(x[j].y - m2);
    x[j] = make_float2(e1, e2);
    s1 += e1; s2 += e2;
  }
#pragma unroll
  for (int s = 32; s > 0; s >>= 1) {
    s1 += __shfl_xor(s1, s, 64);
    s2 += __shfl_xor(s2, s, 64);
  }
  float inv1 = 1.0f / s1, inv2 = 1.0f / s2;

  __syncthreads();  // ALL G reads done before ANY P writes

  {
    // rho is an involution: position pos in the 16-block at 16*bl6 holds
    // x[rho[pos]]. Build pos-ordered short8 pairs -> 2x b128 per row.
    const int rho[16] = {0, 8, 4, 12, 2, 10, 6, 14, 1, 9, 5, 13, 3, 11, 7, 15};
    short a0[16], a1[16];
#pragma unroll
    for (int pos = 0; pos < 16; ++pos) {
      const int j = rho[pos];
      a0[pos] = f2bf(x[j].x * inv1);
      a1[pos] = f2bf(x[j].y * inv2);
    }
    short* dst0 = &P[(2 * p) * 1040 + 16 * bl6];
    short* dst1 = &P[(2 * p + 1) * 1040 + 16 * bl6];
    *(short8*)dst0       = *(short8*)&a0[0];
    *(short8*)(dst0 + 8) = *(short8*)&a0[8];
    *(short8*)dst1       = *(short8*)&a1[0];
    *(short8*)(dst1 + 8) = *(short8*)&a1[8];
  }
  __syncthreads();  // P complete

  // PV: wave w covers k in [w*128, w*128+128)
  const short* __restrict__ Vp = Vt + ((size_t)(bh0 + z) << 16);
  f32x4 acc[4] = {};
#pragma unroll
  for (int ks = 0; ks < 4; ++ks) {
    int k0 = w * 128 + ks * 32;
    short8 a0 = *(const short8*)&P[lm * 1040 + k0 + lq * 8];
#pragma unroll
    for (int b = 0; b < 4; ++b) {
      short8 bv = *(const short8*)&Vp[(size_t)(b * 16 + lm) * 1024 + k0 + lq * 8];
      acc[b] = __builtin_amdgcn_mfma_f32_16x16x32_bf16(a0, bv, acc[b], 0, 0, 0);
    }
  }
  __syncthreads();  // all P reads done; reuse GP for reduction
  float* red = (float*)GP;  // [w=8][q=16][d=64] = 32 KB
#pragma unroll
  for (int b = 0; b < 4; ++b)
#pragma unroll
    for (int r = 0; r < 4; ++r)
      red[(w * 16 + lq * 4 + r) * 64 + b * 16 + lm] = acc[b][r];
  __syncthreads();
  if (tid < 256) {
    int q = tid >> 4, d0 = (tid & 15) * 4;
    float s0 = 0.f, s1_ = 0.f, s2_ = 0.f, s3 = 0.f;
#pragma unroll
    for (int ww = 0; ww < 8; ++ww) {
      const float* rr = &red[(ww * 16 + q) * 64 + d0];
      s0 += rr[0]; s1_ += rr[1]; s2_ += rr[2]; s3 += rr[3];
    }
    short o4[4] = {f2bf(s0), f2bf(s1_), f2bf(s2_), f2bf(s3)};
    *(int2*)&ctx[(((size_t)(bh0 + z)) << 16) + (size_t)(q0 + q) * 64 + d0] = *(int2*)o4;
  }
#undef GROW
}

// ------------------------------------------------- k7: out = ctx @ Wo^T + bo (XCD-swizzled)
__global__ __launch_bounds__(256) void k7_out(
    const short* __restrict__ ctx, const void* __restrict__ Wo,
    const void* __restrict__ bo, void* __restrict__ out,
    const int* __restrict__ flags)
{
  __shared__ __align__(16) char smem[128 * 136 * 2];
  short* As = (short*)smem;
  short* Bs = As + 128 * PITCH;
  short* Ct = (short*)smem;
  const int isf32 = flags[0];
  const int t = threadIdx.x;
  const int lb = blockIdx.x;
  const int m0 = ((lb & 7) * 4 + ((lb >> 3) & 3)) * 128;
  const int n0 = (lb >> 5) * 128;
  const int lane = t & 63, wvi = t >> 6;
  const int wr = wvi >> 1, wc = wvi & 1;
  const int lm = lane & 15, lq = lane >> 4;
  f32x4 acc[4][4] = {};

  for (int k0 = 0; k0 < 1024; k0 += 32) {
    __syncthreads();
#pragma unroll
    for (int i = 0; i < 2; ++i) {
      int l = t + i * 256;
      int row = l >> 2, kk = (l & 3) << 3;
      int n = m0 + row, e = k0 + kk;
      size_t aaddr = (((size_t)((n >> 10) * 16 + (e >> 6))) << 16) + (size_t)((n & 1023) << 6) + (e & 63);
      *(int4*)&As[row * PITCH + kk] = *(const int4*)&ctx[aaddr];
      *(short8*)&Bs[row * PITCH + kk] = ld8(Wo, (size_t)(n0 + row) * 1024 + e, isf32);
    }
    __syncthreads();
    short8 af[4], bf[4];
#pragma unroll
    for (int a = 0; a < 4; ++a) af[a] = *(const short8*)&As[(wr * 64 + a * 16 + lm) * PITCH + lq * 8];
#pragma unroll
    for (int b = 0; b < 4; ++b) bf[b] = *(const short8*)&Bs[(wc * 64 + b * 16 + lm) * PITCH + lq * 8];
#pragma unroll
    for (int a = 0; a < 4; ++a)
#pragma unroll
      for (int b = 0; b < 4; ++b)
        acc[a][b] = __builtin_amdgcn_mfma_f32_16x16x32_bf16(af[a], bf[b], acc[a][b], 0, 0, 0);
  }

  if (isf32) {
#pragma unroll
    for (int a = 0; a < 4; ++a)
#pragma unroll
      for (int b = 0; b < 4; ++b) {
        int col = n0 + wc * 64 + b * 16 + lm;
        float bo_ = ldf(bo, col, 1);
#pragma unroll
        for (int r = 0; r < 4; ++r) {
          int row = m0 + wr * 64 + a * 16 + lq * 4 + r;
          ((float*)out)[(size_t)row * 1024 + col] = acc[a][b][r] + bo_;
        }
      }
    return;
  }
  __syncthreads();
#pragma unroll
  for (int a = 0; a < 4; ++a)
#pragma unroll
    for (int b = 0; b < 4; ++b) {
      int col = wc * 64 + b * 16 + lm;
      float bo_ = ldf(bo, n0 + col, 0);
#pragma unroll
      for (int r = 0; r < 4; ++r) {
        int row = wr * 64 + a * 16 + lq * 4 + r;
        Ct[row * 136 + col] = f2bf(acc[a][b][r] + bo_);
      }
    }
  __syncthreads();
#pragma unroll
  for (int j = 0; j < 8; ++j) {
    int id = t + j * 256;
    int row = id >> 4, c16 = (id & 15) * 8;
    short8 v = *(const short8*)&Ct[row * 136 + c16];
    *(short8*)&((short*)out)[(size_t)(m0 + row) * 1024 + n0 + c16] = v;
  }
}

// ------------------------------------------------- launch
extern "C" void kernel_launch(void* const* d_in, const int* in_sizes, int n_in,
                              void* d_out, int out_size, void* d_ws, size_t ws_size,
                              hipStream_t stream)
{
  const void* x  = d_in[0];
  const void* Wq = d_in[1];
  const void* bq = d_in[2];
  const void* Wk = d_in[3];
  const void* bk = d_in[4];
  const void* Wv = d_in[5];
  const void* bv = d_in[6];
  const void* Wo = d_in[7];
  const void* bo = d_in[8];
  const void* alphap = d_in[9];
  char* ws = (char*)d_ws;

  const size_t PLANE_CT = (size_t)513 * 1024 * 4;  // 2,101,248 B
  const size_t QH_SZ = (size_t)64 * 64 * 1024 * 4; // 16 MiB
  const size_t KH_SZ = (size_t)64 * 64 * 520 * 4;  // 8.125 MiB
  const int K0B_BLOCKS = (524288 + 3 * 131072 + 3 * 128 + 255) / 256;

  // ---- big path layout: Ct-all overlays Qt/Kt/converted-inputs ----
  const size_t B_CT  = 0;
  const size_t B_VT  = 64 * PLANE_CT;            // 134,479,872
  const size_t B_CX  = B_VT + ((size_t)8u << 20);
  const size_t B_QH  = B_CX + ((size_t)8u << 20);
  const size_t B_KH  = B_QH + QH_SZ;
  const size_t B_FL  = B_KH + KH_SZ;
  const size_t B_NEED = B_FL + 256;

  if (ws_size >= B_NEED) {
    short*   Qt   = (short*)(ws);                        // [0, 8M)
    short*   Kt   = (short*)(ws + ((size_t)8u << 20));   // [8M, 16M)
    short*   xb   = (short*)(ws + ((size_t)16u << 20));  // [16M, 24M)  dead after k1
    short*   Wqb  = (short*)(ws + ((size_t)24u << 20));
    short*   Wkb  = (short*)(ws + ((size_t)26u << 20));
    short*   Wvb  = (short*)(ws + ((size_t)28u << 20));
    float*   bqf  = (float*)(ws + ((size_t)30u << 20));
    float*   bkf  = (float*)(ws + ((size_t)30u << 20) + 4096);
    float*   bvf  = (float*)(ws + ((size_t)30u << 20) + 8192);
    short*   Vt   = (short*)(ws + B_VT);
    short*   ctx  = (short*)(ws + B_CX);
    __half2* Ct   = (__half2*)(ws + B_CT);   // overlays [0, 134.5M)
    __half2* Qhat = (__half2*)(ws + B_QH);
    __half2* Khat = (__half2*)(ws + B_KH);
    int*     flags = (int*)(ws + B_FL);

    k0_detect<<<1, 256, 0, stream>>>((const unsigned*)x, alphap, flags);
    k0b_convert<<<K0B_BLOCKS, 256, 0, stream>>>(x, Wq, bq, Wk, bk, Wv, bv,
                                                xb, Wqb, Wkb, Wvb, bqf, bkf, bvf, flags);
    k1_qkv<<<dim3(256, 3), 256, 0, stream>>>(xb, Wqb, bqf, Wkb, bkf, Wvb, bvf, Qt, Kt, Vt);
    kA_qkfft<<<dim3(32, 64), 128, 0, stream>>>(Qt, Kt, Qhat, Khat);
    kB_specmm<<<dim3(8, 9, 64), 256, 0, stream>>>(Qhat, Khat, Ct, flags, 0);
    k4_invfft<<<dim3(33, 64), 256, 0, stream>>>(Ct);
    k56_softmax_av<<<dim3(64, 64), 512, 0, stream>>>(Ct, Vt, ctx, 0);
    k7_out<<<256, 256, 0, stream>>>(ctx, Wo, bo, d_out, flags);
    return;
  }

  // ---- chunked fallback (unreachable given proven ws >= 169M; kept safe) ----
  const size_t VT_OFF = (size_t)17u << 20;
  const size_t CX_OFF = (size_t)25u << 20;
  const size_t QH_OFF = (size_t)33u << 20;
  const size_t KH_OFF = QH_OFF + QH_SZ;
  const size_t FL_OFF = KH_OFF + KH_SZ;
  const size_t XB_OFF = (size_t)58u << 20;

  short*   Qt   = (short*)(ws);
  short*   Kt   = (short*)(ws + ((size_t)8u << 20));
  short*   Vt   = (short*)(ws + VT_OFF);
  short*   ctx  = (short*)(ws + CX_OFF);
  __half2* Ct   = (__half2*)(ws);          // overlays Qt/Kt (dead after kA)
  __half2* Qhat = (__half2*)(ws + QH_OFF);
  __half2* Khat = (__half2*)(ws + KH_OFF);
  int*     flags = (int*)(ws + FL_OFF);
  short*   xb   = (short*)(ws + XB_OFF);
  short*   Wqb  = (short*)(ws + XB_OFF + ((size_t)8u << 20));
  short*   Wkb  = (short*)(ws + XB_OFF + ((size_t)10u << 20));
  short*   Wvb  = (short*)(ws + XB_OFF + ((size_t)12u << 20));
  float*   bqf  = (float*)(ws + XB_OFF + ((size_t)14u << 20));
  float*   bkf  = (float*)(ws + XB_OFF + ((size_t)14u << 20) + 4096);
  float*   bvf  = (float*)(ws + XB_OFF + ((size_t)14u << 20) + 8192);

  k0_detect<<<1, 256, 0, stream>>>((const unsigned*)x, alphap, flags);
  k0b_convert<<<K0B_BLOCKS, 256, 0, stream>>>(x, Wq, bq, Wk, bk, Wv, bv,
                                              xb, Wqb, Wkb, Wvb, bqf, bkf, bvf, flags);
  k1_qkv<<<dim3(256, 3), 256, 0, stream>>>(xb, Wqb, bqf, Wkb, bkf, Wvb, bvf, Qt, Kt, Vt);
  kA_qkfft<<<dim3(32, 64), 128, 0, stream>>>(Qt, Kt, Qhat, Khat);
  for (int c = 0; c < 8; ++c) {
    int bh0 = c * 8;
    kB_specmm<<<dim3(8, 9, 8), 256, 0, stream>>>(Qhat, Khat, Ct, flags, bh0);
    k4_invfft<<<dim3(33, 8), 256, 0, stream>>>(Ct);
    k56_softmax_av<<<dim3(64, 8), 512, 0, stream>>>(Ct, Vt, ctx, bh0);
  }
  k7_out<<<256, 256, 0, stream>>>(ctx, Wo, bo, d_out, flags);
}

// Round 9
// 676.351 us; speedup vs baseline: 1.3046x; 1.3046x over previous
//
#include <hip/hip_runtime.h>
#include <hip/hip_fp16.h>

// SpectralAttention: B=4, S=1024, E=1024, H=16, HD=64.
// Identity: real(ifft2(F*exp(i*phi))) == ifft2(F * cos(phi)) for real scores
// => real spectral gain, Hermitian half-spectrum (v=0..512).
//
// Round-14 (consolidation to proven round-11 config + red-pitch fix):
//  - k4 reverted to ILP-2 (round-13's ILP-4 hit the VGPR cliff: 212 regs,
//    10.9% occupancy, 302 us).
//  - k1 reverted to the f32-reading BK=64 version; k0b prepass dropped
//    (neutral-to-negative; k1 is latency-bound, not conversion-bound).
//  - k56: PV-reduction LDS pitch 64 -> 68 floats (row-stride 64 = 0 mod 32
//    made every store 4-way bank-conflicted; 68 = 4 mod 32 spreads 64 lanes
//    over 32 banks = 2-way = free). GP 33280 -> 34816 B, still 4 blocks/CU.
//
// Chunked layout (~59.9 MiB):  Qt 8M | Kt 8M (both overlaid by per-chunk Ct
//   16.81M) | Vt@17M | ctx@25M | Qhat@33M 16M | Khat 8.125M | flags
// Big layout (~168.4 MiB): Ct-all 128.25M (overlays Qt/Kt) | Vt | ctx |
//   Qhat | Khat | flags

typedef __attribute__((ext_vector_type(8))) short short8;
typedef __attribute__((ext_vector_type(8))) _Float16 half8;
typedef __attribute__((ext_vector_type(4))) float f32x4;

#define PITCH 40    // k7 staging pitch (BK=32)
#define PITCH1 72   // k1 staging pitch (BK=64)

__device__ __forceinline__ float bf2f(short v) {
  return __uint_as_float(((unsigned)(unsigned short)v) << 16);
}
__device__ __forceinline__ short f2bf(float f) {
  unsigned u = __float_as_uint(f);
  u += 0x7FFFu + ((u >> 16) & 1u);  // RNE
  return (short)(u >> 16);
}

__device__ __forceinline__ short8 ld8(const void* p, size_t idx, int isf32) {
  short8 r;
  if (isf32) {
    const float* f = (const float*)p + idx;
    float4 a = *(const float4*)f;
    float4 b = *(const float4*)(f + 4);
    r[0] = f2bf(a.x); r[1] = f2bf(a.y); r[2] = f2bf(a.z); r[3] = f2bf(a.w);
    r[4] = f2bf(b.x); r[5] = f2bf(b.y); r[6] = f2bf(b.z); r[7] = f2bf(b.w);
  } else {
    r = *(const short8*)((const short*)p + idx);
  }
  return r;
}
__device__ __forceinline__ float ldf(const void* p, int idx, int isf32) {
  return isf32 ? ((const float*)p)[idx] : bf2f(((const short*)p)[idx]);
}

__device__ __forceinline__ float2 cmul(float2 a, float2 b) {
  return make_float2(a.x * b.x - a.y * b.y, a.x * b.y + a.y * b.x);
}
__device__ __forceinline__ float2 cmulc(float2 a, float2 b) {  // a * conj(b)
  return make_float2(a.x * b.x + a.y * b.y, a.y * b.x - a.x * b.y);
}
__device__ __forceinline__ float2 cadd(float2 a, float2 b) {
  return make_float2(a.x + b.x, a.y + b.y);
}
__device__ __forceinline__ float2 csub(float2 a, float2 b) {
  return make_float2(a.x - b.x, a.y - b.y);
}

// ================== wave-register 1024-pt FFT (16 in-reg x 64 cross-lane) ==
// Layout: lane l holds z[l + 64*j], j=0..15 (n1 = lane, n2 = reg).
// Forward DIF output: (lane l, reg r) holds F[bitrev4(r) + 16*bitrev6(l)].
// wfft1024_dif<-1> = true DFT (W^-), <+1> = unnormalized inverse (W^+).
// wfft1024_inv2 = exact stage-mirror of dif<-1>; dif(-1) o inv = 1024*I.

template <int SGN>
__device__ __forceinline__ void dft16_dif(float2* x) {
  const float C16[8] = {1.f, 0.92387953f, 0.70710678f, 0.38268343f,
                        0.f, -0.38268343f, -0.70710678f, -0.92387953f};
  const float S16[8] = {0.f, 0.38268343f, 0.70710678f, 0.92387953f,
                        1.f, 0.92387953f, 0.70710678f, 0.38268343f};
#pragma unroll
  for (int h = 8; h >= 1; h >>= 1)
#pragma unroll
    for (int b = 0; b < 16; b += 2 * h)
#pragma unroll
      for (int i = 0; i < h; ++i) {
        const int e = i * (8 / h);
        float2 u = x[b + i], v = x[b + i + h];
        x[b + i] = cadd(u, v);
        float2 d = csub(u, v);
        float2 w = make_float2(C16[e], SGN > 0 ? S16[e] : -S16[e]);
        x[b + i + h] = (e == 0) ? d : cmul(d, w);
      }
}

__device__ __forceinline__ void dit16_inv(float2* x) {
  const float C16[8] = {1.f, 0.92387953f, 0.70710678f, 0.38268343f,
                        0.f, -0.38268343f, -0.70710678f, -0.92387953f};
  const float S16[8] = {0.f, 0.38268343f, 0.70710678f, 0.92387953f,
                        1.f, 0.92387953f, 0.70710678f, 0.38268343f};
#pragma unroll
  for (int h = 1; h <= 8; h <<= 1)
#pragma unroll
    for (int b = 0; b < 16; b += 2 * h)
#pragma unroll
      for (int i = 0; i < h; ++i) {
        const int e = i * (8 / h);
        float2 w = make_float2(C16[e], -S16[e]);
        float2 u = x[b + i];
        float2 vh = (e == 0) ? x[b + i + h] : cmulc(x[b + i + h], w);
        x[b + i] = cadd(u, vh);
        x[b + i + h] = csub(u, vh);
      }
}

template <int SGN>
__device__ __forceinline__ void midtw(float2* x, int lane) {
  const int rho[16] = {0, 8, 4, 12, 2, 10, 6, 14, 1, 9, 5, 13, 3, 11, 7, 15};
  float s, c;
  __sincosf((float)lane * 0.00613592315f, &s, &c);  // 2pi/1024
  float2 w = make_float2(c, SGN > 0 ? s : -s);
  float2 run = w;
  x[8] = cmul(x[8], run);
#pragma unroll
  for (int e = 2; e < 16; ++e) {
    run = cmul(run, w);
    x[rho[e]] = cmul(x[rho[e]], run);
  }
}

template <int SGN>
__device__ __forceinline__ void xlane_dif(float2* x, int lane) {
#pragma unroll
  for (int h = 32; h >= 1; h >>= 1) {
    const int e = (lane & (h - 1)) * (32 / h);
    float s, c;
    __sincosf((float)e * 0.09817477042f, &s, &c);  // 2pi/64
    float2 w = make_float2(c, SGN > 0 ? s : -s);
    const bool hi = (lane & h) != 0;
#pragma unroll
    for (int r = 0; r < 16; ++r) {
      float2 t = x[r];
      float2 p;
      p.x = __shfl_xor(t.x, h, 64);
      p.y = __shfl_xor(t.y, h, 64);
      x[r] = hi ? cmul(csub(p, t), w) : cadd(t, p);
    }
  }
}

template <int SGN>
__device__ __forceinline__ void wfft1024_dif(float2* x, int lane) {
  dft16_dif<SGN>(x);
  midtw<SGN>(x, lane);
  xlane_dif<SGN>(x, lane);
}

// -------- paired (two-row) variants: shared twiddles, 2x ILP per stage ----
template <int SGN>
__device__ __forceinline__ void midtw2(float2* x, float2* y, int lane) {
  const int rho[16] = {0, 8, 4, 12, 2, 10, 6, 14, 1, 9, 5, 13, 3, 11, 7, 15};
  float s, c;
  __sincosf((float)lane * 0.00613592315f, &s, &c);
  float2 w = make_float2(c, SGN > 0 ? s : -s);
  float2 run = w;
  x[8] = cmul(x[8], run);
  y[8] = cmul(y[8], run);
#pragma unroll
  for (int e = 2; e < 16; ++e) {
    run = cmul(run, w);
    x[rho[e]] = cmul(x[rho[e]], run);
    y[rho[e]] = cmul(y[rho[e]], run);
  }
}

__device__ __forceinline__ void midtw_inv2(float2* x, float2* y, int lane) {
  const int rho[16] = {0, 8, 4, 12, 2, 10, 6, 14, 1, 9, 5, 13, 3, 11, 7, 15};
  float s, c;
  __sincosf((float)lane * 0.00613592315f, &s, &c);
  float2 w = make_float2(c, -s);
  float2 run = w;
  x[8] = cmulc(x[8], run);
  y[8] = cmulc(y[8], run);
#pragma unroll
  for (int e = 2; e < 16; ++e) {
    run = cmul(run, w);
    x[rho[e]] = cmulc(x[rho[e]], run);
    y[rho[e]] = cmulc(y[rho[e]], run);
  }
}

template <int SGN>
__device__ __forceinline__ void xlane_dif2(float2* x, float2* y, int lane) {
#pragma unroll
  for (int h = 32; h >= 1; h >>= 1) {
    const int e = (lane & (h - 1)) * (32 / h);
    float s, c;
    __sincosf((float)e * 0.09817477042f, &s, &c);
    float2 w = make_float2(c, SGN > 0 ? s : -s);
    const bool hi = (lane & h) != 0;
#pragma unroll
    for (int r = 0; r < 16; ++r) {
      float2 t = x[r];
      float2 p;
      p.x = __shfl_xor(t.x, h, 64);
      p.y = __shfl_xor(t.y, h, 64);
      x[r] = hi ? cmul(csub(p, t), w) : cadd(t, p);
    }
#pragma unroll
    for (int r = 0; r < 16; ++r) {
      float2 t = y[r];
      float2 p;
      p.x = __shfl_xor(t.x, h, 64);
      p.y = __shfl_xor(t.y, h, 64);
      y[r] = hi ? cmul(csub(p, t), w) : cadd(t, p);
    }
  }
}

__device__ __forceinline__ void xlane_dit_inv2(float2* x, float2* y, int lane) {
#pragma unroll
  for (int h = 1; h <= 32; h <<= 1) {
    const int e = (lane & (h - 1)) * (32 / h);
    float s, c;
    __sincosf((float)e * 0.09817477042f, &s, &c);
    float2 w = make_float2(c, -s);
    const bool hi = (lane & h) != 0;
#pragma unroll
    for (int r = 0; r < 16; ++r) {
      float2 t = x[r];
      if (hi) t = cmulc(t, w);
      float2 p;
      p.x = __shfl_xor(t.x, h, 64);
      p.y = __shfl_xor(t.y, h, 64);
      x[r] = hi ? csub(p, t) : cadd(t, p);
    }
#pragma unroll
    for (int r = 0; r < 16; ++r) {
      float2 t = y[r];
      if (hi) t = cmulc(t, w);
      float2 p;
      p.x = __shfl_xor(t.x, h, 64);
      p.y = __shfl_xor(t.y, h, 64);
      y[r] = hi ? csub(p, t) : cadd(t, p);
    }
  }
}

template <int SGN>
__device__ __forceinline__ void wfft1024_dif2(float2* x, float2* y, int lane) {
  dft16_dif<SGN>(x);
  dft16_dif<SGN>(y);
  midtw2<SGN>(x, y, lane);
  xlane_dif2<SGN>(x, y, lane);
}
__device__ __forceinline__ void wfft1024_inv2(float2* x, float2* y, int lane) {
  xlane_dit_inv2(x, y, lane);
  midtw_inv2(x, y, lane);
  dit16_inv(x);
  dit16_inv(y);
}

// spectral gain; 1/N^2 folded in. alpha==1: cos(atan t) == rsqrt(1+t^2).
__device__ __forceinline__ float gainw(float re, float im, float alpha, bool a1) {
  float mag2 = re * re + im * im;
  float t = 0.5f * __logf(mag2 + 1e-20f);
  if (a1) return __builtin_amdgcn_rsqf(fmaf(t, t, 1.0f)) * (1.0f / 1048576.0f);
  return __cosf(alpha * atanf(t)) * (1.0f / 1048576.0f);
}

// ------------------------------------------------- k0: dtype detect + alpha
__global__ void k0_detect(const unsigned* __restrict__ q,
                          const void* __restrict__ alphap, int* __restrict__ flags) {
  __shared__ float smax[256];
  __shared__ int szero[256];
  int t = threadIdx.x;
  float mx = 0.f; int zc = 0;
  for (int i = t; i < 16384; i += 256) {
    unsigned w = q[i];
    unsigned lo = w & 0xFFFFu;
    float v = fabsf(__uint_as_float(lo << 16));
    if (!(v <= 1e30f)) v = 1e30f;
    mx = fmaxf(mx, v);
    zc += (lo == 0u);
  }
  smax[t] = mx; szero[t] = zc;
  __syncthreads();
  for (int s = 128; s > 0; s >>= 1) {
    if (t < s) { smax[t] = fmaxf(smax[t], smax[t + s]); szero[t] += szero[t + s]; }
    __syncthreads();
  }
  if (t == 0) {
    int isf32 = (smax[0] > 100.f) || (szero[0] > 12288);
    flags[0] = isf32;
    float alpha = isf32 ? *(const float*)alphap : bf2f(*(const short*)alphap);
    ((float*)flags)[1] = alpha;
  }
}

// ------------------------------------------------- k1: QKV projection (XCD-swizzled)
// BK=64. Outputs transposed: O[plane][d][s].
__global__ __launch_bounds__(256) void k1_qkv(
    const void* __restrict__ x,
    const void* __restrict__ Wq, const void* __restrict__ bq,
    const void* __restrict__ Wk, const void* __restrict__ bk,
    const void* __restrict__ Wv, const void* __restrict__ bv,
    short* __restrict__ Qt, short* __restrict__ Kt, short* __restrict__ Vt,
    const int* __restrict__ flags)
{
  __shared__ __align__(16) char smem[128 * PITCH1 * 2 * 2];  // 36864 B
  short* As = (short*)smem;
  short* Bs = As + 128 * PITCH1;
  short* Ct = (short*)smem;  // epilogue overlay (34816 B)
  const int isf32 = flags[0];
  const int t = threadIdx.x;
  const int lb = blockIdx.x;
  const int m0 = ((lb & 7) * 4 + ((lb >> 3) & 3)) * 128;
  const int n0 = (lb >> 5) * 128;
  const int which = blockIdx.y;
  const void* __restrict__ W = (which == 0) ? Wq : (which == 1) ? Wk : Wv;
  const void* __restrict__ bias = (which == 0) ? bq : (which == 1) ? bk : bv;
  const int lane = t & 63, wvi = t >> 6;
  const int wr = wvi >> 1, wc = wvi & 1;
  const int lm = lane & 15, lq = lane >> 4;
  f32x4 acc[4][4] = {};

  for (int k0 = 0; k0 < 1024; k0 += 64) {
    __syncthreads();
#pragma unroll
    for (int i = 0; i < 4; ++i) {
      int l = t + i * 256;
      int row = l >> 3, kk = (l & 7) << 3;
      *(short8*)&As[row * PITCH1 + kk] = ld8(x, (size_t)(m0 + row) * 1024 + k0 + kk, isf32);
      *(short8*)&Bs[row * PITCH1 + kk] = ld8(W, (size_t)(n0 + row) * 1024 + k0 + kk, isf32);
    }
    __syncthreads();
#pragma unroll
    for (int kh = 0; kh < 2; ++kh) {
      short8 af[4], bf[4];
#pragma unroll
      for (int a = 0; a < 4; ++a)
        af[a] = *(const short8*)&As[(wr * 64 + a * 16 + lm) * PITCH1 + kh * 32 + lq * 8];
#pragma unroll
      for (int b = 0; b < 4; ++b)
        bf[b] = *(const short8*)&Bs[(wc * 64 + b * 16 + lm) * PITCH1 + kh * 32 + lq * 8];
#pragma unroll
      for (int a = 0; a < 4; ++a)
#pragma unroll
        for (int b = 0; b < 4; ++b)
          acc[a][b] = __builtin_amdgcn_mfma_f32_16x16x32_bf16(af[a], bf[b], acc[a][b], 0, 0, 0);
    }
  }

  __syncthreads();
#pragma unroll
  for (int a = 0; a < 4; ++a)
#pragma unroll
    for (int b = 0; b < 4; ++b) {
      int col = wc * 64 + b * 16 + lm;
      float bv_ = ldf(bias, n0 + col, isf32);
#pragma unroll
      for (int r = 0; r < 4; ++r) {
        int row = wr * 64 + a * 16 + lq * 4 + r;
        Ct[row * 136 + col] = f2bf(acc[a][b][r] + bv_);
      }
    }
  __syncthreads();

  short* __restrict__ O = (which == 0) ? Qt : (which == 1) ? Kt : Vt;
#pragma unroll
  for (int j = 0; j < 8; ++j) {
    int id = t + j * 256;
    int d128 = id & 127, sg = (id >> 7) * 8;
    short vals[8];
#pragma unroll
    for (int i = 0; i < 8; ++i) vals[i] = Ct[(sg + i) * 136 + d128];
    int col = n0 + d128;
    int h = col >> 6, d = col & 63;
    int bb = m0 >> 10, sbase = (m0 & 1023) + sg;
    *(short8*)&O[(((size_t)(bb * 16 + h)) << 16) + ((size_t)d << 10) + sbase] = *(short8*)vals;
  }
}

// ------------------------------------------------- kA: column FFTs of Q and K
// ONE dispatch, all 64 planes: grid (32, 64), 128 threads (2 waves).
__global__ __launch_bounds__(128) void kA_qkfft(
    const short* __restrict__ Qt, const short* __restrict__ Kt,
    __half2* __restrict__ Qhat, __half2* __restrict__ Khat)
{
  __shared__ float2 sbuf[2][1024];
  const int lane = threadIdx.x & 63, w = threadIdx.x >> 6;
  const int z = blockIdx.y;
  const int bx = blockIdx.x;
  if (bx < 16) {
    const short* qp = Qt + ((size_t)z << 16);
    const int d0 = bx * 4 + w * 2;
    float2 x[16], y[16];
#pragma unroll
    for (int j = 0; j < 16; ++j) {
      x[j] = make_float2(0.125f * bf2f(qp[(d0 << 10) + lane + 64 * j]), 0.f);
      y[j] = make_float2(0.125f * bf2f(qp[((d0 + 1) << 10) + lane + 64 * j]), 0.f);
    }
    wfft1024_dif2<-1>(x, y, lane);
    __half2* o0 = Qhat + (((size_t)(z * 64 + d0)) << 10);
    __half2* o1 = o0 + 1024;
#pragma unroll
    for (int r = 0; r < 16; ++r) {
      o0[lane + 64 * r] = __float22half2_rn(x[r]);
      o1[lane + 64 * r] = __float22half2_rn(y[r]);
    }
  } else {
    const short* kp = Kt + ((size_t)z << 16);
    const int p = (bx - 16) * 2 + w;
    const int d0 = 2 * p;
    float2 x[16];
#pragma unroll
    for (int j = 0; j < 16; ++j)
      x[j] = make_float2(bf2f(kp[(d0 << 10) + lane + 64 * j]),
                         bf2f(kp[((d0 + 1) << 10) + lane + 64 * j]));
    wfft1024_dif<-1>(x, lane);
    const int rho[16] = {0, 8, 4, 12, 2, 10, 6, 14, 1, 9, 5, 13, 3, 11, 7, 15};
    const int bl6 = ((lane & 1) << 5) | ((lane & 2) << 3) | ((lane & 4) << 1) |
                    ((lane & 8) >> 1) | ((lane & 16) >> 3) | ((lane & 32) >> 5);
    float2* buf = sbuf[w];
#pragma unroll
    for (int r = 0; r < 16; ++r) buf[rho[r] + 16 * bl6] = x[r];
    __half2* o0 = Khat + (size_t)(z * 64 + d0) * 520;
    __half2* o1 = o0 + 520;
#pragma unroll 1
    for (int jj = 0; jj < 9; ++jj) {
      int v = lane + 64 * jj;
      if (v <= 512) {
        float2 A = buf[v], B = buf[(1024 - v) & 1023];
        // K1 = (Z + conj(Z~))/2 ; K2 = (Z - conj(Z~))/(2i)
        o0[v] = __float22half2_rn(make_float2((A.x + B.x) * 0.5f, (A.y - B.y) * 0.5f));
        o1[v] = __float22half2_rn(make_float2((A.y + B.y) * 0.5f, (B.x - A.x) * 0.5f));
      }
    }
  }
}

// ------------------------------------------------- kB: F2D = Khat x Qhat^T + gain
// C[v][u-slot], M=64 (v), N=128 (u), K=64 (d). fp16 MFMA, f32 accum.
__global__ __launch_bounds__(256) void kB_specmm(
    const __half2* __restrict__ Qhat, const __half2* __restrict__ Khat,
    __half2* __restrict__ Ct, const int* __restrict__ flags, int bh0)
{
  __shared__ unsigned short Are[64][72], Aim[64][72], Bre[128][72], Bim[128][72];
  const int t = threadIdx.x;
  const int u0 = blockIdx.x * 128;
  const int v0 = blockIdx.y * 64;
  const int zl = blockIdx.z;
  const int z = bh0 + zl;
  const float alpha = ((const float*)flags)[1];
  const bool a1 = (alpha == 1.0f);
  {
    const int d = t >> 2;
    const ushort2* src = (const ushort2*)(Khat + (size_t)(z * 64 + d) * 520);
    int vb = (t & 3) * 16;
#pragma unroll
    for (int j = 0; j < 16; ++j) {
      int v = v0 + vb + j;
      if (v > 519) v = 519;
      ushort2 e = src[v];
      int row = vb + j;
      int dc = d ^ (((row >> 4) & 3) << 4);  // bank-spread swizzle
      Are[row][dc] = e.x;
      Aim[row][dc] = e.y;
    }
    const ushort2* srcb = (const ushort2*)(Qhat + (((size_t)(z * 64 + d)) << 10) + u0);
    int ub = (t & 3) * 32;
#pragma unroll
    for (int j = 0; j < 32; ++j) {
      ushort2 e = srcb[ub + j];
      int row = ub + j;
      int dc = d ^ (((row >> 5) & 3) << 4);
      Bre[row][dc] = e.x;
      Bim[row][dc] = e.y;
    }
  }
  __syncthreads();

  const int lane = t & 63, wc = t >> 6;
  const int lm = lane & 15, lq = lane >> 4;
  f32x4 cre[4][2] = {}, cim[4][2] = {};
#pragma unroll
  for (int ks = 0; ks < 2; ++ks) {
    half8 ar[4], ai[4], aiN[4], br[2], bi[2];
#pragma unroll
    for (int a = 0; a < 4; ++a) {
      int dc = (ks * 32 + lq * 8) ^ ((a & 3) << 4);
      ar[a] = *(const half8*)&Are[a * 16 + lm][dc];
      ai[a] = *(const half8*)&Aim[a * 16 + lm][dc];
      int4 tm = *(int4*)&ai[a];
      tm.x ^= 0x80008000; tm.y ^= 0x80008000; tm.z ^= 0x80008000; tm.w ^= 0x80008000;
      aiN[a] = *(half8*)&tm;
    }
#pragma unroll
    for (int n = 0; n < 2; ++n) {
      int dc = (ks * 32 + lq * 8) ^ ((wc & 3) << 4);
      br[n] = *(const half8*)&Bre[wc * 32 + n * 16 + lm][dc];
      bi[n] = *(const half8*)&Bim[wc * 32 + n * 16 + lm][dc];
    }
#pragma unroll
    for (int a = 0; a < 4; ++a)
#pragma unroll
      for (int n = 0; n < 2; ++n) {
        cre[a][n] = __builtin_amdgcn_mfma_f32_16x16x32_f16(ar[a], br[n], cre[a][n], 0, 0, 0);
        cre[a][n] = __builtin_amdgcn_mfma_f32_16x16x32_f16(aiN[a], bi[n], cre[a][n], 0, 0, 0);
        cim[a][n] = __builtin_amdgcn_mfma_f32_16x16x32_f16(ar[a], bi[n], cim[a][n], 0, 0, 0);
        cim[a][n] = __builtin_amdgcn_mfma_f32_16x16x32_f16(ai[a], br[n], cim[a][n], 0, 0, 0);
      }
  }

  __half2* outp = Ct + (size_t)zl * 513 * 1024 + u0 + wc * 32;
#pragma unroll
  for (int a = 0; a < 4; ++a)
#pragma unroll
    for (int r = 0; r < 4; ++r) {
      int v = v0 + a * 16 + lq * 4 + r;
      if (v < 513) {
#pragma unroll
        for (int n = 0; n < 2; ++n) {
          float re = cre[a][n][r], im = cim[a][n][r];
          float wf = gainw(re, im, alpha, a1);
          outp[(size_t)v * 1024 + n * 16 + lm] =
              __float22half2_rn(make_float2(re * wf, im * wf));
        }
      }
    }
}

// ------------------------------------------------- k4: inverse u-FFT (in place)
// Reads F~[v][u-slot] (scrambled-u), writes G[v][q] natural. Two rows/wave.
__global__ __launch_bounds__(256) void k4_invfft(__half2* __restrict__ Ct)
{
  const int lane = threadIdx.x & 63;
  const int w = threadIdx.x >> 6;
  const int gv0 = blockIdx.x * 8 + w * 2;
  if (gv0 > 512) return;
  const bool has1 = (gv0 + 1 <= 512);
  __half2* __restrict__ row0 = Ct + (size_t)blockIdx.y * 513 * 1024 + ((size_t)gv0 << 10);
  __half2* __restrict__ row1 = row0 + 1024;
  float2 x[16], y[16];
#pragma unroll
  for (int j = 0; j < 16; ++j) x[j] = __half22float2(row0[lane + 64 * j]);
  if (has1) {
#pragma unroll
    for (int j = 0; j < 16; ++j) y[j] = __half22float2(row1[lane + 64 * j]);
  } else {
#pragma unroll
    for (int j = 0; j < 16; ++j) y[j] = make_float2(0.f, 0.f);
  }
  wfft1024_inv2(x, y, lane);
#pragma unroll
  for (int j = 0; j < 16; ++j) row0[lane + 64 * j] = __float22half2_rn(x[j]);
  if (has1) {
#pragma unroll
    for (int j = 0; j < 16; ++j) row1[lane + 64 * j] = __float22half2_rn(y[j]);
  }
}

// ------------------------------------------------- k56: inverse row FFT + softmax + PV
// 512 threads / 8 waves, single round: wave w owns p-pair w (rows 2w, 2w+1).
// Gbuf pitch 2064 B (2-way staging); P scatter via rho-involution reorder
// -> 2x ds_write_b128/row. PV reduction pitch 68 floats (conflict-free).
__global__ __launch_bounds__(512) void k56_softmax_av(
    const __half2* __restrict__ Ct, const short* __restrict__ Vt,
    short* __restrict__ ctx, int bh0)
{
  __shared__ __align__(16) char GP[34816];
  const int tid = threadIdx.x;
  const int q0 = blockIdx.x * 16, z = blockIdx.y;
  const int lane = tid & 63, w = tid >> 6;  // w = 0..7
  const int lm = lane & 15, lq = lane >> 4;
  const __half2* __restrict__ in = Ct + (size_t)z * 513 * 1024;
#define GROW(m) ((__half2*)(GP + (m) * 2064))
  for (int id = tid; id < 2052; id += 512) {
    int v = id >> 2, qq = (id & 3) * 4;
    int4 o = *(const int4*)&in[(size_t)v * 1024 + q0 + qq];
    __half2* op = (__half2*)&o;
#pragma unroll
    for (int i = 0; i < 4; ++i) GROW(qq + i)[v] = op[i];
  }
  short* P = (short*)GP;  // row m at m*1040 shorts
  const int bl6 = ((lane & 1) << 5) | ((lane & 2) << 3) | ((lane & 4) << 1) |
                  ((lane & 8) >> 1) | ((lane & 16) >> 3) | ((lane & 32) >> 5);
  __syncthreads();  // Gbuf ready

  const int p = w;
  const __half2* g1 = GROW(2 * p);
  const __half2* g2 = GROW(2 * p + 1);
  float2 x[16];
#pragma unroll
  for (int j = 0; j < 16; ++j) {
    int v = lane + 64 * j;
    float2 a, b;
    if (v <= 512) {
      a = __half22float2(g1[v]);
      b = __half22float2(g2[v]);
    } else {
      int v2 = 1024 - v;
      float2 aa = __half22float2(g1[v2]), bb = __half22float2(g2[v2]);
      a = make_float2(aa.x, -aa.y);
      b = make_float2(bb.x, -bb.y);
    }
    x[j] = make_float2(a.x - b.y, a.y + b.x);
  }

  wfft1024_dif<1>(x, lane);  // sum_v z W^{+vk}: Re = row 2p, Im = row 2p+1

  float m1 = -3.4e38f, m2 = -3.4e38f;
#pragma unroll
  for (int j = 0; j < 16; ++j) { m1 = fmaxf(m1, x[j].x); m2 = fmaxf(m2, x[j].y); }
#pragma unroll
  for (int s = 32; s > 0; s >>= 1) {
    m1 = fmaxf(m1, __shfl_xor(m1, s, 64));
    m2 = fmaxf(m2, __shfl_xor(m2, s, 64));
  }
  float s1 = 0.f, s2 = 0.f;
#pragma unroll
  for (int j = 0; j < 16; ++j) {
    float e1 = __expf(x[j].x - m1), e2 = __expf(x[j].y - m2);
    x[j] = make_float2(e1, e2);
    s1 += e1; s2 += e2;
  }
#pragma unroll
  for (int s = 32; s > 0; s >>= 1) {
    s1 += __shfl_xor(s1, s, 64);
    s2 += __shfl_xor(s2, s, 64);
  }
  float inv1 = 1.0f / s1, inv2 = 1.0f / s2;

  __syncthreads();  // ALL G reads done before ANY P writes

  {
    // rho is an involution: position pos in the 16-block at 16*bl6 holds
    // x[rho[pos]]. Build pos-ordered short8 pairs -> 2x b128 per row.
    const int rho[16] = {0, 8, 4, 12, 2, 10, 6, 14, 1, 9, 5, 13, 3, 11, 7, 15};
    short a0[16], a1[16];
#pragma unroll
    for (int pos = 0; pos < 16; ++pos) {
      const int j = rho[pos];
      a0[pos] = f2bf(x[j].x * inv1);
      a1[pos] = f2bf(x[j].y * inv2);
    }
    short* dst0 = &P[(2 * p) * 1040 + 16 * bl6];
    short* dst1 = &P[(2 * p + 1) * 1040 + 16 * bl6];
    *(short8*)dst0       = *(short8*)&a0[0];
    *(short8*)(dst0 + 8) = *(short8*)&a0[8];
    *(short8*)dst1       = *(short8*)&a1[0];
    *(short8*)(dst1 + 8) = *(short8*)&a1[8];
  }
  __syncthreads();  // P complete

  // PV: wave w covers k in [w*128, w*128+128)
  const short* __restrict__ Vp = Vt + ((size_t)(bh0 + z) << 16);
  f32x4 acc[4] = {};
#pragma unroll
  for (int ks = 0; ks < 4; ++ks) {
    int k0 = w * 128 + ks * 32;
    short8 a0 = *(const short8*)&P[lm * 1040 + k0 + lq * 8];
#pragma unroll
    for (int b = 0; b < 4; ++b) {
      short8 bv = *(const short8*)&Vp[(size_t)(b * 16 + lm) * 1024 + k0 + lq * 8];
      acc[b] = __builtin_amdgcn_mfma_f32_16x16x32_bf16(a0, bv, acc[b], 0, 0, 0);
    }
  }
  __syncthreads();  // all P reads done; reuse GP for reduction
  // pitch 68 floats: row-stride 68 = 4 mod 32 -> stores spread over all 32
  // banks (2-way = free); 128 rows x 68 x 4 = 34816 B.
  float* red = (float*)GP;
#pragma unroll
  for (int b = 0; b < 4; ++b)
#pragma unroll
    for (int r = 0; r < 4; ++r)
      red[(w * 16 + lq * 4 + r) * 68 + b * 16 + lm] = acc[b][r];
  __syncthreads();
  if (tid < 256) {
    int q = tid >> 4, d0 = (tid & 15) * 4;
    float s0 = 0.f, s1_ = 0.f, s2_ = 0.f, s3 = 0.f;
#pragma unroll
    for (int ww = 0; ww < 8; ++ww) {
      const float* rr = &red[(ww * 16 + q) * 68 + d0];
      s0 += rr[0]; s1_ += rr[1]; s2_ += rr[2]; s3 += rr[3];
    }
    short o4[4] = {f2bf(s0), f2bf(s1_), f2bf(s2_), f2bf(s3)};
    *(int2*)&ctx[(((size_t)(bh0 + z)) << 16) + (size_t)(q0 + q) * 64 + d0] = *(int2*)o4;
  }
#undef GROW
}

// ------------------------------------------------- k7: out = ctx @ Wo^T + bo (XCD-swizzled)
__global__ __launch_bounds__(256) void k7_out(
    const short* __restrict__ ctx, const void* __restrict__ Wo,
    const void* __restrict__ bo, void* __restrict__ out,
    const int* __restrict__ flags)
{
  __shared__ __align__(16) char smem[128 * 136 * 2];
  short* As = (short*)smem;
  short* Bs = As + 128 * PITCH;
  short* Ct = (short*)smem;
  const int isf32 = flags[0];
  const int t = threadIdx.x;
  const int lb = blockIdx.x;
  const int m0 = ((lb & 7) * 4 + ((lb >> 3) & 3)) * 128;
  const int n0 = (lb >> 5) * 128;
  const int lane = t & 63, wvi = t >> 6;
  const int wr = wvi >> 1, wc = wvi & 1;
  const int lm = lane & 15, lq = lane >> 4;
  f32x4 acc[4][4] = {};

  for (int k0 = 0; k0 < 1024; k0 += 32) {
    __syncthreads();
#pragma unroll
    for (int i = 0; i < 2; ++i) {
      int l = t + i * 256;
      int row = l >> 2, kk = (l & 3) << 3;
      int n = m0 + row, e = k0 + kk;
      size_t aaddr = (((size_t)((n >> 10) * 16 + (e >> 6))) << 16) + (size_t)((n & 1023) << 6) + (e & 63);
      *(int4*)&As[row * PITCH + kk] = *(const int4*)&ctx[aaddr];
      *(short8*)&Bs[row * PITCH + kk] = ld8(Wo, (size_t)(n0 + row) * 1024 + e, isf32);
    }
    __syncthreads();
    short8 af[4], bf[4];
#pragma unroll
    for (int a = 0; a < 4; ++a) af[a] = *(const short8*)&As[(wr * 64 + a * 16 + lm) * PITCH + lq * 8];
#pragma unroll
    for (int b = 0; b < 4; ++b) bf[b] = *(const short8*)&Bs[(wc * 64 + b * 16 + lm) * PITCH + lq * 8];
#pragma unroll
    for (int a = 0; a < 4; ++a)
#pragma unroll
      for (int b = 0; b < 4; ++b)
        acc[a][b] = __builtin_amdgcn_mfma_f32_16x16x32_bf16(af[a], bf[b], acc[a][b], 0, 0, 0);
  }

  if (isf32) {
#pragma unroll
    for (int a = 0; a < 4; ++a)
#pragma unroll
      for (int b = 0; b < 4; ++b) {
        int col = n0 + wc * 64 + b * 16 + lm;
        float bo_ = ldf(bo, col, 1);
#pragma unroll
        for (int r = 0; r < 4; ++r) {
          int row = m0 + wr * 64 + a * 16 + lq * 4 + r;
          ((float*)out)[(size_t)row * 1024 + col] = acc[a][b][r] + bo_;
        }
      }
    return;
  }
  __syncthreads();
#pragma unroll
  for (int a = 0; a < 4; ++a)
#pragma unroll
    for (int b = 0; b < 4; ++b) {
      int col = wc * 64 + b * 16 + lm;
      float bo_ = ldf(bo, n0 + col, 0);
#pragma unroll
      for (int r = 0; r < 4; ++r) {
        int row = wr * 64 + a * 16 + lq * 4 + r;
        Ct[row * 136 + col] = f2bf(acc[a][b][r] + bo_);
      }
    }
  __syncthreads();
#pragma unroll
  for (int j = 0; j < 8; ++j) {
    int id = t + j * 256;
    int row = id >> 4, c16 = (id & 15) * 8;
    short8 v = *(const short8*)&Ct[row * 136 + c16];
    *(short8*)&((short*)out)[(size_t)(m0 + row) * 1024 + n0 + c16] = v;
  }
}

// ------------------------------------------------- launch
extern "C" void kernel_launch(void* const* d_in, const int* in_sizes, int n_in,
                              void* d_out, int out_size, void* d_ws, size_t ws_size,
                              hipStream_t stream)
{
  const void* x  = d_in[0];
  const void* Wq = d_in[1];
  const void* bq = d_in[2];
  const void* Wk = d_in[3];
  const void* bk = d_in[4];
  const void* Wv = d_in[5];
  const void* bv = d_in[6];
  const void* Wo = d_in[7];
  const void* bo = d_in[8];
  const void* alphap = d_in[9];
  char* ws = (char*)d_ws;

  const size_t PLANE_CT = (size_t)513 * 1024 * 4;  // 2,101,248 B
  const size_t QH_SZ = (size_t)64 * 64 * 1024 * 4; // 16 MiB
  const size_t KH_SZ = (size_t)64 * 64 * 520 * 4;  // 8.125 MiB

  // ---- big path layout: Ct-all overlays Qt/Kt ----
  const size_t B_CT  = 0;
  const size_t B_VT  = 64 * PLANE_CT;            // 134,479,872
  const size_t B_CX  = B_VT + ((size_t)8u << 20);
  const size_t B_QH  = B_CX + ((size_t)8u << 20);
  const size_t B_KH  = B_QH + QH_SZ;
  const size_t B_FL  = B_KH + KH_SZ;
  const size_t B_NEED = B_FL + 256;

  if (ws_size >= B_NEED) {
    short*   Qt   = (short*)(ws);
    short*   Kt   = (short*)(ws + ((size_t)8u << 20));
    short*   Vt   = (short*)(ws + B_VT);
    short*   ctx  = (short*)(ws + B_CX);
    __half2* Ct   = (__half2*)(ws + B_CT);   // overlays Qt/Kt (dead after kA)
    __half2* Qhat = (__half2*)(ws + B_QH);
    __half2* Khat = (__half2*)(ws + B_KH);
    int*     flags = (int*)(ws + B_FL);

    k0_detect<<<1, 256, 0, stream>>>((const unsigned*)x, alphap, flags);
    k1_qkv<<<dim3(256, 3), 256, 0, stream>>>(x, Wq, bq, Wk, bk, Wv, bv, Qt, Kt, Vt, flags);
    kA_qkfft<<<dim3(32, 64), 128, 0, stream>>>(Qt, Kt, Qhat, Khat);
    kB_specmm<<<dim3(8, 9, 64), 256, 0, stream>>>(Qhat, Khat, Ct, flags, 0);
    k4_invfft<<<dim3(65, 64), 256, 0, stream>>>(Ct);
    k56_softmax_av<<<dim3(64, 64), 512, 0, stream>>>(Ct, Vt, ctx, 0);
    k7_out<<<256, 256, 0, stream>>>(ctx, Wo, bo, d_out, flags);
    return;
  }

  // ---- chunked fallback (proven ~59.9 MiB layout) ----
  const size_t VT_OFF = (size_t)17u << 20;
  const size_t CX_OFF = (size_t)25u << 20;
  const size_t QH_OFF = (size_t)33u << 20;
  const size_t KH_OFF = QH_OFF + QH_SZ;
  const size_t FL_OFF = KH_OFF + KH_SZ;

  short*   Qt   = (short*)(ws);
  short*   Kt   = (short*)(ws + ((size_t)8u << 20));
  short*   Vt   = (short*)(ws + VT_OFF);
  short*   ctx  = (short*)(ws + CX_OFF);
  __half2* Ct   = (__half2*)(ws);          // overlays Qt/Kt (dead after kA)
  __half2* Qhat = (__half2*)(ws + QH_OFF);
  __half2* Khat = (__half2*)(ws + KH_OFF);
  int*     flags = (int*)(ws + FL_OFF);

  k0_detect<<<1, 256, 0, stream>>>((const unsigned*)x, alphap, flags);
  k1_qkv<<<dim3(256, 3), 256, 0, stream>>>(x, Wq, bq, Wk, bk, Wv, bv, Qt, Kt, Vt, flags);
  kA_qkfft<<<dim3(32, 64), 128, 0, stream>>>(Qt, Kt, Qhat, Khat);
  for (int c = 0; c < 8; ++c) {
    int bh0 = c * 8;
    kB_specmm<<<dim3(8, 9, 8), 256, 0, stream>>>(Qhat, Khat, Ct, flags, bh0);
    k4_invfft<<<dim3(65, 8), 256, 0, stream>>>(Ct);
    k56_softmax_av<<<dim3(64, 8), 512, 0, stream>>>(Ct, Vt, ctx, bh0);
  }
  k7_out<<<256, 256, 0, stream>>>(ctx, Wo, bo, d_out, flags);
}

// Round 10
// 611.820 us; speedup vs baseline: 1.4422x; 1.1055x over previous
//
#include <hip/hip_runtime.h>
#include <hip/hip_fp16.h>

// SpectralAttention: B=4, S=1024, E=1024, H=16, HD=64.
// Identity: real(ifft2(F*exp(i*phi))) == ifft2(F * cos(phi)) for real scores
// => real spectral gain, Hermitian half-spectrum (v=0..512).
//
// Round-15: k4 -> MFMA-based inverse u-FFT ("k4m").
//   Memory a[m] = F~[bitrev10(m)]  (m = lane + 64*reg of the fwd scramble).
//   With m = 32h + l', u = 32*br5(l') + br5(h):
//     G[32q1+q0] = sum_h C[q1][h] * ( w^(br5(h)q0) * sum_l' M[h][l'] C[q0][l'] )
//   where C[r][c] = W32^(br5(c)*r), M[h][l'] = a[32h+l'], w = e^(+2pi i/1024).
//   Both stages are 32x32 complex matmuls vs ONE constant matrix, done with
//   the kB-proven mfma_f32_16x16x32_f16 fragment pattern; constants stored
//   hi+lo fp16 (2 MFMA per product) so matrix quantization vanishes.
//   Output is natural-order row-major => in-place write.
// All other kernels identical to round-14 (proven 676 us).

typedef __attribute__((ext_vector_type(8))) short short8;
typedef __attribute__((ext_vector_type(8))) _Float16 half8;
typedef __attribute__((ext_vector_type(4))) float f32x4;

#define PITCH 40    // k7 staging pitch (BK=32)
#define PITCH1 72   // k1 staging pitch (BK=64)
#define TP 40       // k4m fp16 scratch pitch (80 B rows, 16-aligned)

__device__ __forceinline__ float bf2f(short v) {
  return __uint_as_float(((unsigned)(unsigned short)v) << 16);
}
__device__ __forceinline__ short f2bf(float f) {
  unsigned u = __float_as_uint(f);
  u += 0x7FFFu + ((u >> 16) & 1u);  // RNE
  return (short)(u >> 16);
}

__device__ __forceinline__ short8 ld8(const void* p, size_t idx, int isf32) {
  short8 r;
  if (isf32) {
    const float* f = (const float*)p + idx;
    float4 a = *(const float4*)f;
    float4 b = *(const float4*)(f + 4);
    r[0] = f2bf(a.x); r[1] = f2bf(a.y); r[2] = f2bf(a.z); r[3] = f2bf(a.w);
    r[4] = f2bf(b.x); r[5] = f2bf(b.y); r[6] = f2bf(b.z); r[7] = f2bf(b.w);
  } else {
    r = *(const short8*)((const short*)p + idx);
  }
  return r;
}
__device__ __forceinline__ float ldf(const void* p, int idx, int isf32) {
  return isf32 ? ((const float*)p)[idx] : bf2f(((const short*)p)[idx]);
}

__device__ __forceinline__ float2 cmul(float2 a, float2 b) {
  return make_float2(a.x * b.x - a.y * b.y, a.x * b.y + a.y * b.x);
}
__device__ __forceinline__ float2 cadd(float2 a, float2 b) {
  return make_float2(a.x + b.x, a.y + b.y);
}
__device__ __forceinline__ float2 csub(float2 a, float2 b) {
  return make_float2(a.x - b.x, a.y - b.y);
}
__device__ __forceinline__ half8 hneg(half8 v) {
  int4 t = *(int4*)&v;
  t.x ^= 0x80008000; t.y ^= 0x80008000; t.z ^= 0x80008000; t.w ^= 0x80008000;
  return *(half8*)&t;
}

// ================== wave-register 1024-pt forward FFT (kA, k56) ==========
// Layout: lane l holds z[l + 64*j], j=0..15.
// Forward DIF output: (lane l, reg r) holds F[bitrev4(r) + 16*bitrev6(l)].

template <int SGN>
__device__ __forceinline__ void dft16_dif(float2* x) {
  const float C16[8] = {1.f, 0.92387953f, 0.70710678f, 0.38268343f,
                        0.f, -0.38268343f, -0.70710678f, -0.92387953f};
  const float S16[8] = {0.f, 0.38268343f, 0.70710678f, 0.92387953f,
                        1.f, 0.92387953f, 0.70710678f, 0.38268343f};
#pragma unroll
  for (int h = 8; h >= 1; h >>= 1)
#pragma unroll
    for (int b = 0; b < 16; b += 2 * h)
#pragma unroll
      for (int i = 0; i < h; ++i) {
        const int e = i * (8 / h);
        float2 u = x[b + i], v = x[b + i + h];
        x[b + i] = cadd(u, v);
        float2 d = csub(u, v);
        float2 w = make_float2(C16[e], SGN > 0 ? S16[e] : -S16[e]);
        x[b + i + h] = (e == 0) ? d : cmul(d, w);
      }
}

template <int SGN>
__device__ __forceinline__ void midtw(float2* x, int lane) {
  const int rho[16] = {0, 8, 4, 12, 2, 10, 6, 14, 1, 9, 5, 13, 3, 11, 7, 15};
  float s, c;
  __sincosf((float)lane * 0.00613592315f, &s, &c);  // 2pi/1024
  float2 w = make_float2(c, SGN > 0 ? s : -s);
  float2 run = w;
  x[8] = cmul(x[8], run);
#pragma unroll
  for (int e = 2; e < 16; ++e) {
    run = cmul(run, w);
    x[rho[e]] = cmul(x[rho[e]], run);
  }
}

template <int SGN>
__device__ __forceinline__ void xlane_dif(float2* x, int lane) {
#pragma unroll
  for (int h = 32; h >= 1; h >>= 1) {
    const int e = (lane & (h - 1)) * (32 / h);
    float s, c;
    __sincosf((float)e * 0.09817477042f, &s, &c);  // 2pi/64
    float2 w = make_float2(c, SGN > 0 ? s : -s);
    const bool hi = (lane & h) != 0;
#pragma unroll
    for (int r = 0; r < 16; ++r) {
      float2 t = x[r];
      float2 p;
      p.x = __shfl_xor(t.x, h, 64);
      p.y = __shfl_xor(t.y, h, 64);
      x[r] = hi ? cmul(csub(p, t), w) : cadd(t, p);
    }
  }
}

template <int SGN>
__device__ __forceinline__ void wfft1024_dif(float2* x, int lane) {
  dft16_dif<SGN>(x);
  midtw<SGN>(x, lane);
  xlane_dif<SGN>(x, lane);
}

// -------- paired (two-row) forward variant (kA Q-side) ----
template <int SGN>
__device__ __forceinline__ void midtw2(float2* x, float2* y, int lane) {
  const int rho[16] = {0, 8, 4, 12, 2, 10, 6, 14, 1, 9, 5, 13, 3, 11, 7, 15};
  float s, c;
  __sincosf((float)lane * 0.00613592315f, &s, &c);
  float2 w = make_float2(c, SGN > 0 ? s : -s);
  float2 run = w;
  x[8] = cmul(x[8], run);
  y[8] = cmul(y[8], run);
#pragma unroll
  for (int e = 2; e < 16; ++e) {
    run = cmul(run, w);
    x[rho[e]] = cmul(x[rho[e]], run);
    y[rho[e]] = cmul(y[rho[e]], run);
  }
}

template <int SGN>
__device__ __forceinline__ void xlane_dif2(float2* x, float2* y, int lane) {
#pragma unroll
  for (int h = 32; h >= 1; h >>= 1) {
    const int e = (lane & (h - 1)) * (32 / h);
    float s, c;
    __sincosf((float)e * 0.09817477042f, &s, &c);
    float2 w = make_float2(c, SGN > 0 ? s : -s);
    const bool hi = (lane & h) != 0;
#pragma unroll
    for (int r = 0; r < 16; ++r) {
      float2 t = x[r];
      float2 p;
      p.x = __shfl_xor(t.x, h, 64);
      p.y = __shfl_xor(t.y, h, 64);
      x[r] = hi ? cmul(csub(p, t), w) : cadd(t, p);
    }
#pragma unroll
    for (int r = 0; r < 16; ++r) {
      float2 t = y[r];
      float2 p;
      p.x = __shfl_xor(t.x, h, 64);
      p.y = __shfl_xor(t.y, h, 64);
      y[r] = hi ? cmul(csub(p, t), w) : cadd(t, p);
    }
  }
}

template <int SGN>
__device__ __forceinline__ void wfft1024_dif2(float2* x, float2* y, int lane) {
  dft16_dif<SGN>(x);
  dft16_dif<SGN>(y);
  midtw2<SGN>(x, y, lane);
  xlane_dif2<SGN>(x, y, lane);
}

// spectral gain; 1/N^2 folded in. alpha==1: cos(atan t) == rsqrt(1+t^2).
__device__ __forceinline__ float gainw(float re, float im, float alpha, bool a1) {
  float mag2 = re * re + im * im;
  float t = 0.5f * __logf(mag2 + 1e-20f);
  if (a1) return __builtin_amdgcn_rsqf(fmaf(t, t, 1.0f)) * (1.0f / 1048576.0f);
  return __cosf(alpha * atanf(t)) * (1.0f / 1048576.0f);
}

// ------------------------------------------------- k0: dtype detect + alpha
__global__ void k0_detect(const unsigned* __restrict__ q,
                          const void* __restrict__ alphap, int* __restrict__ flags) {
  __shared__ float smax[256];
  __shared__ int szero[256];
  int t = threadIdx.x;
  float mx = 0.f; int zc = 0;
  for (int i = t; i < 16384; i += 256) {
    unsigned w = q[i];
    unsigned lo = w & 0xFFFFu;
    float v = fabsf(__uint_as_float(lo << 16));
    if (!(v <= 1e30f)) v = 1e30f;
    mx = fmaxf(mx, v);
    zc += (lo == 0u);
  }
  smax[t] = mx; szero[t] = zc;
  __syncthreads();
  for (int s = 128; s > 0; s >>= 1) {
    if (t < s) { smax[t] = fmaxf(smax[t], smax[t + s]); szero[t] += szero[t + s]; }
    __syncthreads();
  }
  if (t == 0) {
    int isf32 = (smax[0] > 100.f) || (szero[0] > 12288);
    flags[0] = isf32;
    float alpha = isf32 ? *(const float*)alphap : bf2f(*(const short*)alphap);
    ((float*)flags)[1] = alpha;
  }
}

// ------------------------------------------------- k1: QKV projection (XCD-swizzled)
// BK=64. Outputs transposed: O[plane][d][s].
__global__ __launch_bounds__(256) void k1_qkv(
    const void* __restrict__ x,
    const void* __restrict__ Wq, const void* __restrict__ bq,
    const void* __restrict__ Wk, const void* __restrict__ bk,
    const void* __restrict__ Wv, const void* __restrict__ bv,
    short* __restrict__ Qt, short* __restrict__ Kt, short* __restrict__ Vt,
    const int* __restrict__ flags)
{
  __shared__ __align__(16) char smem[128 * PITCH1 * 2 * 2];  // 36864 B
  short* As = (short*)smem;
  short* Bs = As + 128 * PITCH1;
  short* Ct = (short*)smem;  // epilogue overlay (34816 B)
  const int isf32 = flags[0];
  const int t = threadIdx.x;
  const int lb = blockIdx.x;
  const int m0 = ((lb & 7) * 4 + ((lb >> 3) & 3)) * 128;
  const int n0 = (lb >> 5) * 128;
  const int which = blockIdx.y;
  const void* __restrict__ W = (which == 0) ? Wq : (which == 1) ? Wk : Wv;
  const void* __restrict__ bias = (which == 0) ? bq : (which == 1) ? bk : bv;
  const int lane = t & 63, wvi = t >> 6;
  const int wr = wvi >> 1, wc = wvi & 1;
  const int lm = lane & 15, lq = lane >> 4;
  f32x4 acc[4][4] = {};

  for (int k0 = 0; k0 < 1024; k0 += 64) {
    __syncthreads();
#pragma unroll
    for (int i = 0; i < 4; ++i) {
      int l = t + i * 256;
      int row = l >> 3, kk = (l & 7) << 3;
      *(short8*)&As[row * PITCH1 + kk] = ld8(x, (size_t)(m0 + row) * 1024 + k0 + kk, isf32);
      *(short8*)&Bs[row * PITCH1 + kk] = ld8(W, (size_t)(n0 + row) * 1024 + k0 + kk, isf32);
    }
    __syncthreads();
#pragma unroll
    for (int kh = 0; kh < 2; ++kh) {
      short8 af[4], bf[4];
#pragma unroll
      for (int a = 0; a < 4; ++a)
        af[a] = *(const short8*)&As[(wr * 64 + a * 16 + lm) * PITCH1 + kh * 32 + lq * 8];
#pragma unroll
      for (int b = 0; b < 4; ++b)
        bf[b] = *(const short8*)&Bs[(wc * 64 + b * 16 + lm) * PITCH1 + kh * 32 + lq * 8];
#pragma unroll
      for (int a = 0; a < 4; ++a)
#pragma unroll
        for (int b = 0; b < 4; ++b)
          acc[a][b] = __builtin_amdgcn_mfma_f32_16x16x32_bf16(af[a], bf[b], acc[a][b], 0, 0, 0);
    }
  }

  __syncthreads();
#pragma unroll
  for (int a = 0; a < 4; ++a)
#pragma unroll
    for (int b = 0; b < 4; ++b) {
      int col = wc * 64 + b * 16 + lm;
      float bv_ = ldf(bias, n0 + col, isf32);
#pragma unroll
      for (int r = 0; r < 4; ++r) {
        int row = wr * 64 + a * 16 + lq * 4 + r;
        Ct[row * 136 + col] = f2bf(acc[a][b][r] + bv_);
      }
    }
  __syncthreads();

  short* __restrict__ O = (which == 0) ? Qt : (which == 1) ? Kt : Vt;
#pragma unroll
  for (int j = 0; j < 8; ++j) {
    int id = t + j * 256;
    int d128 = id & 127, sg = (id >> 7) * 8;
    short vals[8];
#pragma unroll
    for (int i = 0; i < 8; ++i) vals[i] = Ct[(sg + i) * 136 + d128];
    int col = n0 + d128;
    int h = col >> 6, d = col & 63;
    int bb = m0 >> 10, sbase = (m0 & 1023) + sg;
    *(short8*)&O[(((size_t)(bb * 16 + h)) << 16) + ((size_t)d << 10) + sbase] = *(short8*)vals;
  }
}

// ------------------------------------------------- kA: column FFTs of Q and K
// ONE dispatch, all 64 planes: grid (32, 64), 128 threads (2 waves).
__global__ __launch_bounds__(128) void kA_qkfft(
    const short* __restrict__ Qt, const short* __restrict__ Kt,
    __half2* __restrict__ Qhat, __half2* __restrict__ Khat)
{
  __shared__ float2 sbuf[2][1024];
  const int lane = threadIdx.x & 63, w = threadIdx.x >> 6;
  const int z = blockIdx.y;
  const int bx = blockIdx.x;
  if (bx < 16) {
    const short* qp = Qt + ((size_t)z << 16);
    const int d0 = bx * 4 + w * 2;
    float2 x[16], y[16];
#pragma unroll
    for (int j = 0; j < 16; ++j) {
      x[j] = make_float2(0.125f * bf2f(qp[(d0 << 10) + lane + 64 * j]), 0.f);
      y[j] = make_float2(0.125f * bf2f(qp[((d0 + 1) << 10) + lane + 64 * j]), 0.f);
    }
    wfft1024_dif2<-1>(x, y, lane);
    __half2* o0 = Qhat + (((size_t)(z * 64 + d0)) << 10);
    __half2* o1 = o0 + 1024;
#pragma unroll
    for (int r = 0; r < 16; ++r) {
      o0[lane + 64 * r] = __float22half2_rn(x[r]);
      o1[lane + 64 * r] = __float22half2_rn(y[r]);
    }
  } else {
    const short* kp = Kt + ((size_t)z << 16);
    const int p = (bx - 16) * 2 + w;
    const int d0 = 2 * p;
    float2 x[16];
#pragma unroll
    for (int j = 0; j < 16; ++j)
      x[j] = make_float2(bf2f(kp[(d0 << 10) + lane + 64 * j]),
                         bf2f(kp[((d0 + 1) << 10) + lane + 64 * j]));
    wfft1024_dif<-1>(x, lane);
    const int rho[16] = {0, 8, 4, 12, 2, 10, 6, 14, 1, 9, 5, 13, 3, 11, 7, 15};
    const int bl6 = ((lane & 1) << 5) | ((lane & 2) << 3) | ((lane & 4) << 1) |
                    ((lane & 8) >> 1) | ((lane & 16) >> 3) | ((lane & 32) >> 5);
    float2* buf = sbuf[w];
#pragma unroll
    for (int r = 0; r < 16; ++r) buf[rho[r] + 16 * bl6] = x[r];
    __half2* o0 = Khat + (size_t)(z * 64 + d0) * 520;
    __half2* o1 = o0 + 520;
#pragma unroll 1
    for (int jj = 0; jj < 9; ++jj) {
      int v = lane + 64 * jj;
      if (v <= 512) {
        float2 A = buf[v], B = buf[(1024 - v) & 1023];
        // K1 = (Z + conj(Z~))/2 ; K2 = (Z - conj(Z~))/(2i)
        o0[v] = __float22half2_rn(make_float2((A.x + B.x) * 0.5f, (A.y - B.y) * 0.5f));
        o1[v] = __float22half2_rn(make_float2((A.y + B.y) * 0.5f, (B.x - A.x) * 0.5f));
      }
    }
  }
}

// ------------------------------------------------- kB: F2D = Khat x Qhat^T + gain
// C[v][u-slot], M=64 (v), N=128 (u), K=64 (d). fp16 MFMA, f32 accum.
__global__ __launch_bounds__(256) void kB_specmm(
    const __half2* __restrict__ Qhat, const __half2* __restrict__ Khat,
    __half2* __restrict__ Ct, const int* __restrict__ flags, int bh0)
{
  __shared__ unsigned short Are[64][72], Aim[64][72], Bre[128][72], Bim[128][72];
  const int t = threadIdx.x;
  const int u0 = blockIdx.x * 128;
  const int v0 = blockIdx.y * 64;
  const int zl = blockIdx.z;
  const int z = bh0 + zl;
  const float alpha = ((const float*)flags)[1];
  const bool a1 = (alpha == 1.0f);
  {
    const int d = t >> 2;
    const ushort2* src = (const ushort2*)(Khat + (size_t)(z * 64 + d) * 520);
    int vb = (t & 3) * 16;
#pragma unroll
    for (int j = 0; j < 16; ++j) {
      int v = v0 + vb + j;
      if (v > 519) v = 519;
      ushort2 e = src[v];
      int row = vb + j;
      int dc = d ^ (((row >> 4) & 3) << 4);  // bank-spread swizzle
      Are[row][dc] = e.x;
      Aim[row][dc] = e.y;
    }
    const ushort2* srcb = (const ushort2*)(Qhat + (((size_t)(z * 64 + d)) << 10) + u0);
    int ub = (t & 3) * 32;
#pragma unroll
    for (int j = 0; j < 32; ++j) {
      ushort2 e = srcb[ub + j];
      int row = ub + j;
      int dc = d ^ (((row >> 5) & 3) << 4);
      Bre[row][dc] = e.x;
      Bim[row][dc] = e.y;
    }
  }
  __syncthreads();

  const int lane = t & 63, wc = t >> 6;
  const int lm = lane & 15, lq = lane >> 4;
  f32x4 cre[4][2] = {}, cim[4][2] = {};
#pragma unroll
  for (int ks = 0; ks < 2; ++ks) {
    half8 ar[4], ai[4], aiN[4], br[2], bi[2];
#pragma unroll
    for (int a = 0; a < 4; ++a) {
      int dc = (ks * 32 + lq * 8) ^ ((a & 3) << 4);
      ar[a] = *(const half8*)&Are[a * 16 + lm][dc];
      ai[a] = *(const half8*)&Aim[a * 16 + lm][dc];
      aiN[a] = hneg(ai[a]);
    }
#pragma unroll
    for (int n = 0; n < 2; ++n) {
      int dc = (ks * 32 + lq * 8) ^ ((wc & 3) << 4);
      br[n] = *(const half8*)&Bre[wc * 32 + n * 16 + lm][dc];
      bi[n] = *(const half8*)&Bim[wc * 32 + n * 16 + lm][dc];
    }
#pragma unroll
    for (int a = 0; a < 4; ++a)
#pragma unroll
      for (int n = 0; n < 2; ++n) {
        cre[a][n] = __builtin_amdgcn_mfma_f32_16x16x32_f16(ar[a], br[n], cre[a][n], 0, 0, 0);
        cre[a][n] = __builtin_amdgcn_mfma_f32_16x16x32_f16(aiN[a], bi[n], cre[a][n], 0, 0, 0);
        cim[a][n] = __builtin_amdgcn_mfma_f32_16x16x32_f16(ar[a], bi[n], cim[a][n], 0, 0, 0);
        cim[a][n] = __builtin_amdgcn_mfma_f32_16x16x32_f16(ai[a], br[n], cim[a][n], 0, 0, 0);
      }
  }

  __half2* outp = Ct + (size_t)zl * 513 * 1024 + u0 + wc * 32;
#pragma unroll
  for (int a = 0; a < 4; ++a)
#pragma unroll
    for (int r = 0; r < 4; ++r) {
      int v = v0 + a * 16 + lq * 4 + r;
      if (v < 513) {
#pragma unroll
        for (int n = 0; n < 2; ++n) {
          float re = cre[a][n][r], im = cim[a][n][r];
          float wf = gainw(re, im, alpha, a1);
          outp[(size_t)v * 1024 + n * 16 + lm] =
              __float22half2_rn(make_float2(re * wf, im * wf));
        }
      }
    }
}

// ------------------------------------------------- k4m: MFMA inverse u-FFT (in place)
// a[m] = F~[br10(m)]. Two 32x32 complex matmul stages vs constant
// C[r][c] = W32^(br5(c)*r) (hi/lo fp16 split), mid twiddle w^(br5(h)*q0).
// Output G[q] natural order. 256 thr / 4 waves; wave processes 4 rows.
__global__ __launch_bounds__(256) void k4_invfft(__half2* __restrict__ Ct, int nrows)
{
  __shared__ unsigned short CM[4][32][TP];      // CreHi, CreLo, CimHi, CimLo
  __shared__ unsigned short SC[4][4][32][TP];   // [wave][Mre, MimNeg, Ttre, TtimNeg]
  const int tid = threadIdx.x;
  const int lane = tid & 63, w = tid >> 6;
  const int lm = lane & 15, lq = lane >> 4;

  // build constants: [r][c] = W32^(br5(c)*r), W32 = e^{+2pi i/32}
  for (int i = tid; i < 1024; i += 256) {
    int r = i >> 5, c = i & 31;
    int brc = ((c & 1) << 4) | ((c & 2) << 2) | (c & 4) | ((c & 8) >> 2) | ((c & 16) >> 4);
    float ang = (float)((brc * r) & 31) * 0.19634954084936207f;  // 2pi/32
    float sv, cv;
    __sincosf(ang, &sv, &cv);
    __half chh = __float2half(cv), shh = __float2half(sv);
    CM[0][r][c] = __half_as_ushort(chh);
    CM[1][r][c] = __half_as_ushort(__float2half(cv - __half2float(chh)));
    CM[2][r][c] = __half_as_ushort(shh);
    CM[3][r][c] = __half_as_ushort(__float2half(sv - __half2float(shh)));
  }
  __syncthreads();

  half8 cf[4][2];
#pragma unroll
  for (int cmp = 0; cmp < 4; ++cmp)
#pragma unroll
    for (int t = 0; t < 2; ++t)
      cf[cmp][t] = *(const half8*)&CM[cmp][t * 16 + lm][lq * 8];

  unsigned short (*MRE)[TP] = SC[w][0];
  unsigned short (*MIM)[TP] = SC[w][1];  // holds -Im
  unsigned short (*TRE)[TP] = SC[w][2];
  unsigned short (*TIM)[TP] = SC[w][3];  // holds -Im

  const int slot = blockIdx.x * 4 + w;
  __half2* __restrict__ plane = Ct + (size_t)blockIdx.y * 513 * 1024;

#pragma unroll 1
  for (int rr = 0; rr < 4; ++rr) {
    const int vrow = slot * 4 + rr;
    const bool act = (vrow < nrows);
    __half2* __restrict__ row = plane + ((size_t)(act ? vrow : 0) << 10);
    // load: chunk c = lane + 64k covers m = 4c..4c+3 (coalesced int4)
    int4 ch4[4];
#pragma unroll
    for (int k = 0; k < 4; ++k)
      ch4[k] = act ? *(const int4*)&row[4 * (lane + 64 * k)] : make_int4(0, 0, 0, 0);
    // stage: m = 4*lane+256k+j -> h = (lane>>3)+8k, l' = 4*(lane&7)+j
#pragma unroll
    for (int k = 0; k < 4; ++k) {
      const unsigned* e = (const unsigned*)&ch4[k];
      unsigned short re4[4], im4[4];
#pragma unroll
      for (int j = 0; j < 4; ++j) {
        unsigned u = e[j];
        re4[j] = (unsigned short)(u & 0xFFFFu);
        im4[j] = (unsigned short)((u >> 16) ^ 0x8000u);  // negated im
      }
      int h = (lane >> 3) + 8 * k, c0 = 4 * (lane & 7);
      *(int2*)&MRE[h][c0] = *(int2*)re4;
      *(int2*)&MIM[h][c0] = *(int2*)im4;
    }
    __syncthreads();  // B1: M staged

    // stage-1: N[h][q0] = sum_l' M[h][l'] * C[q0][l']   (A=M rows h, B=C rows q0)
    half8 mre[2], mng[2], mps[2];
#pragma unroll
    for (int t = 0; t < 2; ++t) {
      mre[t] = *(const half8*)&MRE[t * 16 + lm][lq * 8];
      mng[t] = *(const half8*)&MIM[t * 16 + lm][lq * 8];
      mps[t] = hneg(mng[t]);
    }
    f32x4 ar[2][2] = {}, ai[2][2] = {};
#pragma unroll
    for (int i = 0; i < 2; ++i)
#pragma unroll
      for (int j = 0; j < 2; ++j) {
        ar[i][j] = __builtin_amdgcn_mfma_f32_16x16x32_f16(mre[i], cf[0][j], ar[i][j], 0, 0, 0);
        ar[i][j] = __builtin_amdgcn_mfma_f32_16x16x32_f16(mre[i], cf[1][j], ar[i][j], 0, 0, 0);
        ar[i][j] = __builtin_amdgcn_mfma_f32_16x16x32_f16(mng[i], cf[2][j], ar[i][j], 0, 0, 0);
        ar[i][j] = __builtin_amdgcn_mfma_f32_16x16x32_f16(mng[i], cf[3][j], ar[i][j], 0, 0, 0);
        ai[i][j] = __builtin_amdgcn_mfma_f32_16x16x32_f16(mre[i], cf[2][j], ai[i][j], 0, 0, 0);
        ai[i][j] = __builtin_amdgcn_mfma_f32_16x16x32_f16(mre[i], cf[3][j], ai[i][j], 0, 0, 0);
        ai[i][j] = __builtin_amdgcn_mfma_f32_16x16x32_f16(mps[i], cf[0][j], ai[i][j], 0, 0, 0);
        ai[i][j] = __builtin_amdgcn_mfma_f32_16x16x32_f16(mps[i], cf[1][j], ai[i][j], 0, 0, 0);
      }

    // twiddle w^(br5(h)*q0) and transposed store T^T[q0][h] (im negated)
#pragma unroll
    for (int i = 0; i < 2; ++i)
#pragma unroll
      for (int j = 0; j < 2; ++j) {
        unsigned short tr4[4], ti4[4];
#pragma unroll
        for (int r = 0; r < 4; ++r) {
          int h = i * 16 + lq * 4 + r;
          int q0 = j * 16 + lm;
          int brh = ((h & 1) << 4) | ((h & 2) << 2) | (h & 4) | ((h & 8) >> 2) | ((h & 16) >> 4);
          float ang = (float)(brh * q0) * 0.006135923151542565f;  // 2pi/1024
          float sv, cv;
          __sincosf(ang, &sv, &cv);
          float nre = ar[i][j][r], nim = ai[i][j][r];
          float tre = cv * nre - sv * nim;
          float tim = cv * nim + sv * nre;
          tr4[r] = __half_as_ushort(__float2half(tre));
          ti4[r] = __half_as_ushort(__float2half(-tim));
        }
        *(int2*)&TRE[j * 16 + lm][i * 16 + lq * 4] = *(int2*)tr4;
        *(int2*)&TIM[j * 16 + lm][i * 16 + lq * 4] = *(int2*)ti4;
      }
    __syncthreads();  // B2: T staged (also drains M reads before next overwrite)

    // stage-2: G[q1][q0] = sum_h C[q1][h] * T[h][q0]  (A=C rows q1, B=T^T rows q0)
    half8 tre[2], tng[2], tps[2];
#pragma unroll
    for (int t = 0; t < 2; ++t) {
      tre[t] = *(const half8*)&TRE[t * 16 + lm][lq * 8];
      tng[t] = *(const half8*)&TIM[t * 16 + lm][lq * 8];
      tps[t] = hneg(tng[t]);
    }
    f32x4 gr[2][2] = {}, gi[2][2] = {};
#pragma unroll
    for (int i = 0; i < 2; ++i)
#pragma unroll
      for (int j = 0; j < 2; ++j) {
        gr[i][j] = __builtin_amdgcn_mfma_f32_16x16x32_f16(cf[0][i], tre[j], gr[i][j], 0, 0, 0);
        gr[i][j] = __builtin_amdgcn_mfma_f32_16x16x32_f16(cf[1][i], tre[j], gr[i][j], 0, 0, 0);
        gr[i][j] = __builtin_amdgcn_mfma_f32_16x16x32_f16(cf[2][i], tng[j], gr[i][j], 0, 0, 0);
        gr[i][j] = __builtin_amdgcn_mfma_f32_16x16x32_f16(cf[3][i], tng[j], gr[i][j], 0, 0, 0);
        gi[i][j] = __builtin_amdgcn_mfma_f32_16x16x32_f16(cf[0][i], tps[j], gi[i][j], 0, 0, 0);
        gi[i][j] = __builtin_amdgcn_mfma_f32_16x16x32_f16(cf[1][i], tps[j], gi[i][j], 0, 0, 0);
        gi[i][j] = __builtin_amdgcn_mfma_f32_16x16x32_f16(cf[2][i], tre[j], gi[i][j], 0, 0, 0);
        gi[i][j] = __builtin_amdgcn_mfma_f32_16x16x32_f16(cf[3][i], tre[j], gi[i][j], 0, 0, 0);
      }

    if (act) {
#pragma unroll
      for (int i = 0; i < 2; ++i)
#pragma unroll
        for (int j = 0; j < 2; ++j)
#pragma unroll
          for (int r = 0; r < 4; ++r) {
            int q = 512 * i + 128 * lq + 32 * r + 16 * j + lm;
            row[q] = __float22half2_rn(make_float2(gr[i][j][r], gi[i][j][r]));
          }
    }
  }
}

// ------------------------------------------------- k56: inverse row FFT + softmax + PV
// [round-14 version, proven 187 us]
__global__ __launch_bounds__(512) void k56_softmax_av(
    const __half2* __restrict__ Ct, const short* __restrict__ Vt,
    short* __restrict__ ctx, int bh0)
{
  __shared__ __align__(16) char GP[34816];
  const int tid = threadIdx.x;
  const int q0 = blockIdx.x * 16, z = blockIdx.y;
  const int lane = tid & 63, w = tid >> 6;  // w = 0..7
  const int lm = lane & 15, lq = lane >> 4;
  const __half2* __restrict__ in = Ct + (size_t)z * 513 * 1024;
#define GROW(m) ((__half2*)(GP + (m) * 2064))
  for (int id = tid; id < 2052; id += 512) {
    int v = id >> 2, qq = (id & 3) * 4;
    int4 o = *(const int4*)&in[(size_t)v * 1024 + q0 + qq];
    __half2* op = (__half2*)&o;
#pragma unroll
    for (int i = 0; i < 4; ++i) GROW(qq + i)[v] = op[i];
  }
  short* P = (short*)GP;  // row m at m*1040 shorts
  const int bl6 = ((lane & 1) << 5) | ((lane & 2) << 3) | ((lane & 4) << 1) |
                  ((lane & 8) >> 1) | ((lane & 16) >> 3) | ((lane & 32) >> 5);
  __syncthreads();  // Gbuf ready

  const int p = w;
  const __half2* g1 = GROW(2 * p);
  const __half2* g2 = GROW(2 * p + 1);
  float2 x[16];
#pragma unroll
  for (int j = 0; j < 16; ++j) {
    int v = lane + 64 * j;
    float2 a, b;
    if (v <= 512) {
      a = __half22float2(g1[v]);
      b = __half22float2(g2[v]);
    } else {
      int v2 = 1024 - v;
      float2 aa = __half22float2(g1[v2]), bb = __half22float2(g2[v2]);
      a = make_float2(aa.x, -aa.y);
      b = make_float2(bb.x, -bb.y);
    }
    x[j] = make_float2(a.x - b.y, a.y + b.x);
  }

  wfft1024_dif<1>(x, lane);  // sum_v z W^{+vk}: Re = row 2p, Im = row 2p+1

  float m1 = -3.4e38f, m2 = -3.4e38f;
#pragma unroll
  for (int j = 0; j < 16; ++j) { m1 = fmaxf(m1, x[j].x); m2 = fmaxf(m2, x[j].y); }
#pragma unroll
  for (int s = 32; s > 0; s >>= 1) {
    m1 = fmaxf(m1, __shfl_xor(m1, s, 64));
    m2 = fmaxf(m2, __shfl_xor(m2, s, 64));
  }
  float s1 = 0.f, s2 = 0.f;
#pragma unroll
  for (int j = 0; j < 16; ++j) {
    float e1 = __expf(x[j].x - m1), e2 = __expf(x[j].y - m2);
    x[j] = make_float2(e1, e2);
    s1 += e1; s2 += e2;
  }
#pragma unroll
  for (int s = 32; s > 0; s >>= 1) {
    s1 += __shfl_xor(s1, s, 64);
    s2 += __shfl_xor(s2, s, 64);
  }
  float inv1 = 1.0f / s1, inv2 = 1.0f / s2;

  __syncthreads();  // ALL G reads done before ANY P writes

  {
    const int rho[16] = {0, 8, 4, 12, 2, 10, 6, 14, 1, 9, 5, 13, 3, 11, 7, 15};
    short a0[16], a1[16];
#pragma unroll
    for (int pos = 0; pos < 16; ++pos) {
      const int j = rho[pos];
      a0[pos] = f2bf(x[j].x * inv1);
      a1[pos] = f2bf(x[j].y * inv2);
    }
    short* dst0 = &P[(2 * p) * 1040 + 16 * bl6];
    short* dst1 = &P[(2 * p + 1) * 1040 + 16 * bl6];
    *(short8*)dst0       = *(short8*)&a0[0];
    *(short8*)(dst0 + 8) = *(short8*)&a0[8];
    *(short8*)dst1       = *(short8*)&a1[0];
    *(short8*)(dst1 + 8) = *(short8*)&a1[8];
  }
  __syncthreads();  // P complete

  const short* __restrict__ Vp = Vt + ((size_t)(bh0 + z) << 16);
  f32x4 acc[4] = {};
#pragma unroll
  for (int ks = 0; ks < 4; ++ks) {
    int k0 = w * 128 + ks * 32;
    short8 a0 = *(const short8*)&P[lm * 1040 + k0 + lq * 8];
#pragma unroll
    for (int b = 0; b < 4; ++b) {
      short8 bv = *(const short8*)&Vp[(size_t)(b * 16 + lm) * 1024 + k0 + lq * 8];
      acc[b] = __builtin_amdgcn_mfma_f32_16x16x32_bf16(a0, bv, acc[b], 0, 0, 0);
    }
  }
  __syncthreads();  // all P reads done; reuse GP for reduction
  float* red = (float*)GP;  // pitch 68 floats (conflict-free); 128*68*4 = 34816 B
#pragma unroll
  for (int b = 0; b < 4; ++b)
#pragma unroll
    for (int r = 0; r < 4; ++r)
      red[(w * 16 + lq * 4 + r) * 68 + b * 16 + lm] = acc[b][r];
  __syncthreads();
  if (tid < 256) {
    int q = tid >> 4, d0 = (tid & 15) * 4;
    float s0 = 0.f, s1_ = 0.f, s2_ = 0.f, s3 = 0.f;
#pragma unroll
    for (int ww = 0; ww < 8; ++ww) {
      const float* rr = &red[(ww * 16 + q) * 68 + d0];
      s0 += rr[0]; s1_ += rr[1]; s2_ += rr[2]; s3 += rr[3];
    }
    short o4[4] = {f2bf(s0), f2bf(s1_), f2bf(s2_), f2bf(s3)};
    *(int2*)&ctx[(((size_t)(bh0 + z)) << 16) + (size_t)(q0 + q) * 64 + d0] = *(int2*)o4;
  }
#undef GROW
}

// ------------------------------------------------- k7: out = ctx @ Wo^T + bo (XCD-swizzled)
__global__ __launch_bounds__(256) void k7_out(
    const short* __restrict__ ctx, const void* __restrict__ Wo,
    const void* __restrict__ bo, void* __restrict__ out,
    const int* __restrict__ flags)
{
  __shared__ __align__(16) char smem[128 * 136 * 2];
  short* As = (short*)smem;
  short* Bs = As + 128 * PITCH;
  short* Ct = (short*)smem;
  const int isf32 = flags[0];
  const int t = threadIdx.x;
  const int lb = blockIdx.x;
  const int m0 = ((lb & 7) * 4 + ((lb >> 3) & 3)) * 128;
  const int n0 = (lb >> 5) * 128;
  const int lane = t & 63, wvi = t >> 6;
  const int wr = wvi >> 1, wc = wvi & 1;
  const int lm = lane & 15, lq = lane >> 4;
  f32x4 acc[4][4] = {};

  for (int k0 = 0; k0 < 1024; k0 += 32) {
    __syncthreads();
#pragma unroll
    for (int i = 0; i < 2; ++i) {
      int l = t + i * 256;
      int row = l >> 2, kk = (l & 3) << 3;
      int n = m0 + row, e = k0 + kk;
      size_t aaddr = (((size_t)((n >> 10) * 16 + (e >> 6))) << 16) + (size_t)((n & 1023) << 6) + (e & 63);
      *(int4*)&As[row * PITCH + kk] = *(const int4*)&ctx[aaddr];
      *(short8*)&Bs[row * PITCH + kk] = ld8(Wo, (size_t)(n0 + row) * 1024 + e, isf32);
    }
    __syncthreads();
    short8 af[4], bf[4];
#pragma unroll
    for (int a = 0; a < 4; ++a) af[a] = *(const short8*)&As[(wr * 64 + a * 16 + lm) * PITCH + lq * 8];
#pragma unroll
    for (int b = 0; b < 4; ++b) bf[b] = *(const short8*)&Bs[(wc * 64 + b * 16 + lm) * PITCH + lq * 8];
#pragma unroll
    for (int a = 0; a < 4; ++a)
#pragma unroll
      for (int b = 0; b < 4; ++b)
        acc[a][b] = __builtin_amdgcn_mfma_f32_16x16x32_bf16(af[a], bf[b], acc[a][b], 0, 0, 0);
  }

  if (isf32) {
#pragma unroll
    for (int a = 0; a < 4; ++a)
#pragma unroll
      for (int b = 0; b < 4; ++b) {
        int col = n0 + wc * 64 + b * 16 + lm;
        float bo_ = ldf(bo, col, 1);
#pragma unroll
        for (int r = 0; r < 4; ++r) {
          int row = m0 + wr * 64 + a * 16 + lq * 4 + r;
          ((float*)out)[(size_t)row * 1024 + col] = acc[a][b][r] + bo_;
        }
      }
    return;
  }
  __syncthreads();
#pragma unroll
  for (int a = 0; a < 4; ++a)
#pragma unroll
    for (int b = 0; b < 4; ++b) {
      int col = wc * 64 + b * 16 + lm;
      float bo_ = ldf(bo, n0 + col, 0);
#pragma unroll
      for (int r = 0; r < 4; ++r) {
        int row = wr * 64 + a * 16 + lq * 4 + r;
        Ct[row * 136 + col] = f2bf(acc[a][b][r] + bo_);
      }
    }
  __syncthreads();
#pragma unroll
  for (int j = 0; j < 8; ++j) {
    int id = t + j * 256;
    int row = id >> 4, c16 = (id & 15) * 8;
    short8 v = *(const short8*)&Ct[row * 136 + c16];
    *(short8*)&((short*)out)[(size_t)(m0 + row) * 1024 + n0 + c16] = v;
  }
}

// ------------------------------------------------- launch
extern "C" void kernel_launch(void* const* d_in, const int* in_sizes, int n_in,
                              void* d_out, int out_size, void* d_ws, size_t ws_size,
                              hipStream_t stream)
{
  const void* x  = d_in[0];
  const void* Wq = d_in[1];
  const void* bq = d_in[2];
  const void* Wk = d_in[3];
  const void* bk = d_in[4];
  const void* Wv = d_in[5];
  const void* bv = d_in[6];
  const void* Wo = d_in[7];
  const void* bo = d_in[8];
  const void* alphap = d_in[9];
  char* ws = (char*)d_ws;

  const size_t PLANE_CT = (size_t)513 * 1024 * 4;  // 2,101,248 B
  const size_t QH_SZ = (size_t)64 * 64 * 1024 * 4; // 16 MiB
  const size_t KH_SZ = (size_t)64 * 64 * 520 * 4;  // 8.125 MiB

  // ---- big path layout: Ct-all overlays Qt/Kt ----
  const size_t B_CT  = 0;
  const size_t B_VT  = 64 * PLANE_CT;            // 134,479,872
  const size_t B_CX  = B_VT + ((size_t)8u << 20);
  const size_t B_QH  = B_CX + ((size_t)8u << 20);
  const size_t B_KH  = B_QH + QH_SZ;
  const size_t B_FL  = B_KH + KH_SZ;
  const size_t B_NEED = B_FL + 256;

  if (ws_size >= B_NEED) {
    short*   Qt   = (short*)(ws);
    short*   Kt   = (short*)(ws + ((size_t)8u << 20));
    short*   Vt   = (short*)(ws + B_VT);
    short*   ctx  = (short*)(ws + B_CX);
    __half2* Ct   = (__half2*)(ws + B_CT);   // overlays Qt/Kt (dead after kA)
    __half2* Qhat = (__half2*)(ws + B_QH);
    __half2* Khat = (__half2*)(ws + B_KH);
    int*     flags = (int*)(ws + B_FL);

    k0_detect<<<1, 256, 0, stream>>>((const unsigned*)x, alphap, flags);
    k1_qkv<<<dim3(256, 3), 256, 0, stream>>>(x, Wq, bq, Wk, bk, Wv, bv, Qt, Kt, Vt, flags);
    kA_qkfft<<<dim3(32, 64), 128, 0, stream>>>(Qt, Kt, Qhat, Khat);
    kB_specmm<<<dim3(8, 9, 64), 256, 0, stream>>>(Qhat, Khat, Ct, flags, 0);
    k4_invfft<<<dim3(33, 64), 256, 0, stream>>>(Ct, 513);
    k56_softmax_av<<<dim3(64, 64), 512, 0, stream>>>(Ct, Vt, ctx, 0);
    k7_out<<<256, 256, 0, stream>>>(ctx, Wo, bo, d_out, flags);
    return;
  }

  // ---- chunked fallback (proven ~59.9 MiB layout) ----
  const size_t VT_OFF = (size_t)17u << 20;
  const size_t CX_OFF = (size_t)25u << 20;
  const size_t QH_OFF = (size_t)33u << 20;
  const size_t KH_OFF = QH_OFF + QH_SZ;
  const size_t FL_OFF = KH_OFF + KH_SZ;

  short*   Qt   = (short*)(ws);
  short*   Kt   = (short*)(ws + ((size_t)8u << 20));
  short*   Vt   = (short*)(ws + VT_OFF);
  short*   ctx  = (short*)(ws + CX_OFF);
  __half2* Ct   = (__half2*)(ws);          // overlays Qt/Kt (dead after kA)
  __half2* Qhat = (__half2*)(ws + QH_OFF);
  __half2* Khat = (__half2*)(ws + KH_OFF);
  int*     flags = (int*)(ws + FL_OFF);

  k0_detect<<<1, 256, 0, stream>>>((const unsigned*)x, alphap, flags);
  k1_qkv<<<dim3(256, 3), 256, 0, stream>>>(x, Wq, bq, Wk, bk, Wv, bv, Qt, Kt, Vt, flags);
  kA_qkfft<<<dim3(32, 64), 128, 0, stream>>>(Qt, Kt, Qhat, Khat);
  for (int c = 0; c < 8; ++c) {
    int bh0 = c * 8;
    kB_specmm<<<dim3(8, 9, 8), 256, 0, stream>>>(Qhat, Khat, Ct, flags, bh0);
    k4_invfft<<<dim3(33, 8), 256, 0, stream>>>(Ct, 513);
    k56_softmax_av<<<dim3(64, 8), 512, 0, stream>>>(Ct, Vt, ctx, bh0);
  }
  k7_out<<<256, 256, 0, stream>>>(ctx, Wo, bo, d_out, flags);
}

// Round 11
// 584.001 us; speedup vs baseline: 1.5109x; 1.0476x over previous
//
#include <hip/hip_runtime.h>
#include <hip/hip_fp16.h>

// SpectralAttention: B=4, S=1024, E=1024, H=16, HD=64.
// Identity: real(ifft2(F*exp(i*phi))) == ifft2(F * cos(phi)) for real scores
// => real spectral gain, Hermitian half-spectrum (v=0..512).
//
// Round-16: k56 -> MFMA row-inverse-FFT ("k56m"), same two-stage 32x32
// matmul formulation as k4m but WITHOUT bitrev:
//   v = v0+32v1, k = k0+32k1:
//   S[k0+32k1] = sum_v0 D[k1][v0] * ( W^{+v0 k0} * sum_v1 M[v0][v1] D[k0][v1] )
//   with D[r][c] = W32^{+rc} (hi/lo fp16 split), M[v0][v1] = z[v0+32v1].
// Output fragments [k1][k0]; per-wave LDS transpose tile linearizes rows so
// lane l owns k in [16l,16l+16) -> P written as 2x b128 (FFT + scatter both
// replaced). Softmax on fragments + shfl reduce. Wave-private scratch
// (M -> T -> ST reuse, in-wave ordering). 8 waves, 1 complex row each.
// All other kernels identical to round-15 (proven 612 us).

typedef __attribute__((ext_vector_type(8))) short short8;
typedef __attribute__((ext_vector_type(8))) _Float16 half8;
typedef __attribute__((ext_vector_type(4))) float f32x4;

#define PITCH 40    // k7 staging pitch (BK=32)
#define PITCH1 72   // k1 staging pitch (BK=64)
#define TP 40       // fp16 scratch pitch (80 B rows, 16-aligned)

__device__ __forceinline__ float bf2f(short v) {
  return __uint_as_float(((unsigned)(unsigned short)v) << 16);
}
__device__ __forceinline__ short f2bf(float f) {
  unsigned u = __float_as_uint(f);
  u += 0x7FFFu + ((u >> 16) & 1u);  // RNE
  return (short)(u >> 16);
}

__device__ __forceinline__ short8 ld8(const void* p, size_t idx, int isf32) {
  short8 r;
  if (isf32) {
    const float* f = (const float*)p + idx;
    float4 a = *(const float4*)f;
    float4 b = *(const float4*)(f + 4);
    r[0] = f2bf(a.x); r[1] = f2bf(a.y); r[2] = f2bf(a.z); r[3] = f2bf(a.w);
    r[4] = f2bf(b.x); r[5] = f2bf(b.y); r[6] = f2bf(b.z); r[7] = f2bf(b.w);
  } else {
    r = *(const short8*)((const short*)p + idx);
  }
  return r;
}
__device__ __forceinline__ float ldf(const void* p, int idx, int isf32) {
  return isf32 ? ((const float*)p)[idx] : bf2f(((const short*)p)[idx]);
}

__device__ __forceinline__ float2 cmul(float2 a, float2 b) {
  return make_float2(a.x * b.x - a.y * b.y, a.x * b.y + a.y * b.x);
}
__device__ __forceinline__ float2 cadd(float2 a, float2 b) {
  return make_float2(a.x + b.x, a.y + b.y);
}
__device__ __forceinline__ float2 csub(float2 a, float2 b) {
  return make_float2(a.x - b.x, a.y - b.y);
}
__device__ __forceinline__ half8 hneg(half8 v) {
  int4 t = *(int4*)&v;
  t.x ^= 0x80008000; t.y ^= 0x80008000; t.z ^= 0x80008000; t.w ^= 0x80008000;
  return *(half8*)&t;
}

// ================== wave-register 1024-pt forward FFT (kA only now) ======
template <int SGN>
__device__ __forceinline__ void dft16_dif(float2* x) {
  const float C16[8] = {1.f, 0.92387953f, 0.70710678f, 0.38268343f,
                        0.f, -0.38268343f, -0.70710678f, -0.92387953f};
  const float S16[8] = {0.f, 0.38268343f, 0.70710678f, 0.92387953f,
                        1.f, 0.92387953f, 0.70710678f, 0.38268343f};
#pragma unroll
  for (int h = 8; h >= 1; h >>= 1)
#pragma unroll
    for (int b = 0; b < 16; b += 2 * h)
#pragma unroll
      for (int i = 0; i < h; ++i) {
        const int e = i * (8 / h);
        float2 u = x[b + i], v = x[b + i + h];
        x[b + i] = cadd(u, v);
        float2 d = csub(u, v);
        float2 w = make_float2(C16[e], SGN > 0 ? S16[e] : -S16[e]);
        x[b + i + h] = (e == 0) ? d : cmul(d, w);
      }
}

template <int SGN>
__device__ __forceinline__ void midtw(float2* x, int lane) {
  const int rho[16] = {0, 8, 4, 12, 2, 10, 6, 14, 1, 9, 5, 13, 3, 11, 7, 15};
  float s, c;
  __sincosf((float)lane * 0.00613592315f, &s, &c);  // 2pi/1024
  float2 w = make_float2(c, SGN > 0 ? s : -s);
  float2 run = w;
  x[8] = cmul(x[8], run);
#pragma unroll
  for (int e = 2; e < 16; ++e) {
    run = cmul(run, w);
    x[rho[e]] = cmul(x[rho[e]], run);
  }
}

template <int SGN>
__device__ __forceinline__ void xlane_dif(float2* x, int lane) {
#pragma unroll
  for (int h = 32; h >= 1; h >>= 1) {
    const int e = (lane & (h - 1)) * (32 / h);
    float s, c;
    __sincosf((float)e * 0.09817477042f, &s, &c);  // 2pi/64
    float2 w = make_float2(c, SGN > 0 ? s : -s);
    const bool hi = (lane & h) != 0;
#pragma unroll
    for (int r = 0; r < 16; ++r) {
      float2 t = x[r];
      float2 p;
      p.x = __shfl_xor(t.x, h, 64);
      p.y = __shfl_xor(t.y, h, 64);
      x[r] = hi ? cmul(csub(p, t), w) : cadd(t, p);
    }
  }
}

template <int SGN>
__device__ __forceinline__ void wfft1024_dif(float2* x, int lane) {
  dft16_dif<SGN>(x);
  midtw<SGN>(x, lane);
  xlane_dif<SGN>(x, lane);
}

// -------- paired (two-row) forward variant (kA Q-side) ----
template <int SGN>
__device__ __forceinline__ void midtw2(float2* x, float2* y, int lane) {
  const int rho[16] = {0, 8, 4, 12, 2, 10, 6, 14, 1, 9, 5, 13, 3, 11, 7, 15};
  float s, c;
  __sincosf((float)lane * 0.00613592315f, &s, &c);
  float2 w = make_float2(c, SGN > 0 ? s : -s);
  float2 run = w;
  x[8] = cmul(x[8], run);
  y[8] = cmul(y[8], run);
#pragma unroll
  for (int e = 2; e < 16; ++e) {
    run = cmul(run, w);
    x[rho[e]] = cmul(x[rho[e]], run);
    y[rho[e]] = cmul(y[rho[e]], run);
  }
}

template <int SGN>
__device__ __forceinline__ void xlane_dif2(float2* x, float2* y, int lane) {
#pragma unroll
  for (int h = 32; h >= 1; h >>= 1) {
    const int e = (lane & (h - 1)) * (32 / h);
    float s, c;
    __sincosf((float)e * 0.09817477042f, &s, &c);
    float2 w = make_float2(c, SGN > 0 ? s : -s);
    const bool hi = (lane & h) != 0;
#pragma unroll
    for (int r = 0; r < 16; ++r) {
      float2 t = x[r];
      float2 p;
      p.x = __shfl_xor(t.x, h, 64);
      p.y = __shfl_xor(t.y, h, 64);
      x[r] = hi ? cmul(csub(p, t), w) : cadd(t, p);
    }
#pragma unroll
    for (int r = 0; r < 16; ++r) {
      float2 t = y[r];
      float2 p;
      p.x = __shfl_xor(t.x, h, 64);
      p.y = __shfl_xor(t.y, h, 64);
      y[r] = hi ? cmul(csub(p, t), w) : cadd(t, p);
    }
  }
}

template <int SGN>
__device__ __forceinline__ void wfft1024_dif2(float2* x, float2* y, int lane) {
  dft16_dif<SGN>(x);
  dft16_dif<SGN>(y);
  midtw2<SGN>(x, y, lane);
  xlane_dif2<SGN>(x, y, lane);
}

// spectral gain; 1/N^2 folded in. alpha==1: cos(atan t) == rsqrt(1+t^2).
__device__ __forceinline__ float gainw(float re, float im, float alpha, bool a1) {
  float mag2 = re * re + im * im;
  float t = 0.5f * __logf(mag2 + 1e-20f);
  if (a1) return __builtin_amdgcn_rsqf(fmaf(t, t, 1.0f)) * (1.0f / 1048576.0f);
  return __cosf(alpha * atanf(t)) * (1.0f / 1048576.0f);
}

// ------------------------------------------------- k0: dtype detect + alpha
__global__ void k0_detect(const unsigned* __restrict__ q,
                          const void* __restrict__ alphap, int* __restrict__ flags) {
  __shared__ float smax[256];
  __shared__ int szero[256];
  int t = threadIdx.x;
  float mx = 0.f; int zc = 0;
  for (int i = t; i < 16384; i += 256) {
    unsigned w = q[i];
    unsigned lo = w & 0xFFFFu;
    float v = fabsf(__uint_as_float(lo << 16));
    if (!(v <= 1e30f)) v = 1e30f;
    mx = fmaxf(mx, v);
    zc += (lo == 0u);
  }
  smax[t] = mx; szero[t] = zc;
  __syncthreads();
  for (int s = 128; s > 0; s >>= 1) {
    if (t < s) { smax[t] = fmaxf(smax[t], smax[t + s]); szero[t] += szero[t + s]; }
    __syncthreads();
  }
  if (t == 0) {
    int isf32 = (smax[0] > 100.f) || (szero[0] > 12288);
    flags[0] = isf32;
    float alpha = isf32 ? *(const float*)alphap : bf2f(*(const short*)alphap);
    ((float*)flags)[1] = alpha;
  }
}

// ------------------------------------------------- k1: QKV projection (XCD-swizzled)
// BK=64. Outputs transposed: O[plane][d][s].
__global__ __launch_bounds__(256) void k1_qkv(
    const void* __restrict__ x,
    const void* __restrict__ Wq, const void* __restrict__ bq,
    const void* __restrict__ Wk, const void* __restrict__ bk,
    const void* __restrict__ Wv, const void* __restrict__ bv,
    short* __restrict__ Qt, short* __restrict__ Kt, short* __restrict__ Vt,
    const int* __restrict__ flags)
{
  __shared__ __align__(16) char smem[128 * PITCH1 * 2 * 2];  // 36864 B
  short* As = (short*)smem;
  short* Bs = As + 128 * PITCH1;
  short* Ct = (short*)smem;  // epilogue overlay (34816 B)
  const int isf32 = flags[0];
  const int t = threadIdx.x;
  const int lb = blockIdx.x;
  const int m0 = ((lb & 7) * 4 + ((lb >> 3) & 3)) * 128;
  const int n0 = (lb >> 5) * 128;
  const int which = blockIdx.y;
  const void* __restrict__ W = (which == 0) ? Wq : (which == 1) ? Wk : Wv;
  const void* __restrict__ bias = (which == 0) ? bq : (which == 1) ? bk : bv;
  const int lane = t & 63, wvi = t >> 6;
  const int wr = wvi >> 1, wc = wvi & 1;
  const int lm = lane & 15, lq = lane >> 4;
  f32x4 acc[4][4] = {};

  for (int k0 = 0; k0 < 1024; k0 += 64) {
    __syncthreads();
#pragma unroll
    for (int i = 0; i < 4; ++i) {
      int l = t + i * 256;
      int row = l >> 3, kk = (l & 7) << 3;
      *(short8*)&As[row * PITCH1 + kk] = ld8(x, (size_t)(m0 + row) * 1024 + k0 + kk, isf32);
      *(short8*)&Bs[row * PITCH1 + kk] = ld8(W, (size_t)(n0 + row) * 1024 + k0 + kk, isf32);
    }
    __syncthreads();
#pragma unroll
    for (int kh = 0; kh < 2; ++kh) {
      short8 af[4], bf[4];
#pragma unroll
      for (int a = 0; a < 4; ++a)
        af[a] = *(const short8*)&As[(wr * 64 + a * 16 + lm) * PITCH1 + kh * 32 + lq * 8];
#pragma unroll
      for (int b = 0; b < 4; ++b)
        bf[b] = *(const short8*)&Bs[(wc * 64 + b * 16 + lm) * PITCH1 + kh * 32 + lq * 8];
#pragma unroll
      for (int a = 0; a < 4; ++a)
#pragma unroll
        for (int b = 0; b < 4; ++b)
          acc[a][b] = __builtin_amdgcn_mfma_f32_16x16x32_bf16(af[a], bf[b], acc[a][b], 0, 0, 0);
    }
  }

  __syncthreads();
#pragma unroll
  for (int a = 0; a < 4; ++a)
#pragma unroll
    for (int b = 0; b < 4; ++b) {
      int col = wc * 64 + b * 16 + lm;
      float bv_ = ldf(bias, n0 + col, isf32);
#pragma unroll
      for (int r = 0; r < 4; ++r) {
        int row = wr * 64 + a * 16 + lq * 4 + r;
        Ct[row * 136 + col] = f2bf(acc[a][b][r] + bv_);
      }
    }
  __syncthreads();

  short* __restrict__ O = (which == 0) ? Qt : (which == 1) ? Kt : Vt;
#pragma unroll
  for (int j = 0; j < 8; ++j) {
    int id = t + j * 256;
    int d128 = id & 127, sg = (id >> 7) * 8;
    short vals[8];
#pragma unroll
    for (int i = 0; i < 8; ++i) vals[i] = Ct[(sg + i) * 136 + d128];
    int col = n0 + d128;
    int h = col >> 6, d = col & 63;
    int bb = m0 >> 10, sbase = (m0 & 1023) + sg;
    *(short8*)&O[(((size_t)(bb * 16 + h)) << 16) + ((size_t)d << 10) + sbase] = *(short8*)vals;
  }
}

// ------------------------------------------------- kA: column FFTs of Q and K
// ONE dispatch, all 64 planes: grid (32, 64), 128 threads (2 waves).
__global__ __launch_bounds__(128) void kA_qkfft(
    const short* __restrict__ Qt, const short* __restrict__ Kt,
    __half2* __restrict__ Qhat, __half2* __restrict__ Khat)
{
  __shared__ float2 sbuf[2][1024];
  const int lane = threadIdx.x & 63, w = threadIdx.x >> 6;
  const int z = blockIdx.y;
  const int bx = blockIdx.x;
  if (bx < 16) {
    const short* qp = Qt + ((size_t)z << 16);
    const int d0 = bx * 4 + w * 2;
    float2 x[16], y[16];
#pragma unroll
    for (int j = 0; j < 16; ++j) {
      x[j] = make_float2(0.125f * bf2f(qp[(d0 << 10) + lane + 64 * j]), 0.f);
      y[j] = make_float2(0.125f * bf2f(qp[((d0 + 1) << 10) + lane + 64 * j]), 0.f);
    }
    wfft1024_dif2<-1>(x, y, lane);
    __half2* o0 = Qhat + (((size_t)(z * 64 + d0)) << 10);
    __half2* o1 = o0 + 1024;
#pragma unroll
    for (int r = 0; r < 16; ++r) {
      o0[lane + 64 * r] = __float22half2_rn(x[r]);
      o1[lane + 64 * r] = __float22half2_rn(y[r]);
    }
  } else {
    const short* kp = Kt + ((size_t)z << 16);
    const int p = (bx - 16) * 2 + w;
    const int d0 = 2 * p;
    float2 x[16];
#pragma unroll
    for (int j = 0; j < 16; ++j)
      x[j] = make_float2(bf2f(kp[(d0 << 10) + lane + 64 * j]),
                         bf2f(kp[((d0 + 1) << 10) + lane + 64 * j]));
    wfft1024_dif<-1>(x, lane);
    const int rho[16] = {0, 8, 4, 12, 2, 10, 6, 14, 1, 9, 5, 13, 3, 11, 7, 15};
    const int bl6 = ((lane & 1) << 5) | ((lane & 2) << 3) | ((lane & 4) << 1) |
                    ((lane & 8) >> 1) | ((lane & 16) >> 3) | ((lane & 32) >> 5);
    float2* buf = sbuf[w];
#pragma unroll
    for (int r = 0; r < 16; ++r) buf[rho[r] + 16 * bl6] = x[r];
    __half2* o0 = Khat + (size_t)(z * 64 + d0) * 520;
    __half2* o1 = o0 + 520;
#pragma unroll 1
    for (int jj = 0; jj < 9; ++jj) {
      int v = lane + 64 * jj;
      if (v <= 512) {
        float2 A = buf[v], B = buf[(1024 - v) & 1023];
        // K1 = (Z + conj(Z~))/2 ; K2 = (Z - conj(Z~))/(2i)
        o0[v] = __float22half2_rn(make_float2((A.x + B.x) * 0.5f, (A.y - B.y) * 0.5f));
        o1[v] = __float22half2_rn(make_float2((A.y + B.y) * 0.5f, (B.x - A.x) * 0.5f));
      }
    }
  }
}

// ------------------------------------------------- kB: F2D = Khat x Qhat^T + gain
// C[v][u-slot], M=64 (v), N=128 (u), K=64 (d). fp16 MFMA, f32 accum.
__global__ __launch_bounds__(256) void kB_specmm(
    const __half2* __restrict__ Qhat, const __half2* __restrict__ Khat,
    __half2* __restrict__ Ct, const int* __restrict__ flags, int bh0)
{
  __shared__ unsigned short Are[64][72], Aim[64][72], Bre[128][72], Bim[128][72];
  const int t = threadIdx.x;
  const int u0 = blockIdx.x * 128;
  const int v0 = blockIdx.y * 64;
  const int zl = blockIdx.z;
  const int z = bh0 + zl;
  const float alpha = ((const float*)flags)[1];
  const bool a1 = (alpha == 1.0f);
  {
    const int d = t >> 2;
    const ushort2* src = (const ushort2*)(Khat + (size_t)(z * 64 + d) * 520);
    int vb = (t & 3) * 16;
#pragma unroll
    for (int j = 0; j < 16; ++j) {
      int v = v0 + vb + j;
      if (v > 519) v = 519;
      ushort2 e = src[v];
      int row = vb + j;
      int dc = d ^ (((row >> 4) & 3) << 4);  // bank-spread swizzle
      Are[row][dc] = e.x;
      Aim[row][dc] = e.y;
    }
    const ushort2* srcb = (const ushort2*)(Qhat + (((size_t)(z * 64 + d)) << 10) + u0);
    int ub = (t & 3) * 32;
#pragma unroll
    for (int j = 0; j < 32; ++j) {
      ushort2 e = srcb[ub + j];
      int row = ub + j;
      int dc = d ^ (((row >> 5) & 3) << 4);
      Bre[row][dc] = e.x;
      Bim[row][dc] = e.y;
    }
  }
  __syncthreads();

  const int lane = t & 63, wc = t >> 6;
  const int lm = lane & 15, lq = lane >> 4;
  f32x4 cre[4][2] = {}, cim[4][2] = {};
#pragma unroll
  for (int ks = 0; ks < 2; ++ks) {
    half8 ar[4], ai[4], aiN[4], br[2], bi[2];
#pragma unroll
    for (int a = 0; a < 4; ++a) {
      int dc = (ks * 32 + lq * 8) ^ ((a & 3) << 4);
      ar[a] = *(const half8*)&Are[a * 16 + lm][dc];
      ai[a] = *(const half8*)&Aim[a * 16 + lm][dc];
      aiN[a] = hneg(ai[a]);
    }
#pragma unroll
    for (int n = 0; n < 2; ++n) {
      int dc = (ks * 32 + lq * 8) ^ ((wc & 3) << 4);
      br[n] = *(const half8*)&Bre[wc * 32 + n * 16 + lm][dc];
      bi[n] = *(const half8*)&Bim[wc * 32 + n * 16 + lm][dc];
    }
#pragma unroll
    for (int a = 0; a < 4; ++a)
#pragma unroll
      for (int n = 0; n < 2; ++n) {
        cre[a][n] = __builtin_amdgcn_mfma_f32_16x16x32_f16(ar[a], br[n], cre[a][n], 0, 0, 0);
        cre[a][n] = __builtin_amdgcn_mfma_f32_16x16x32_f16(aiN[a], bi[n], cre[a][n], 0, 0, 0);
        cim[a][n] = __builtin_amdgcn_mfma_f32_16x16x32_f16(ar[a], bi[n], cim[a][n], 0, 0, 0);
        cim[a][n] = __builtin_amdgcn_mfma_f32_16x16x32_f16(ai[a], br[n], cim[a][n], 0, 0, 0);
      }
  }

  __half2* outp = Ct + (size_t)zl * 513 * 1024 + u0 + wc * 32;
#pragma unroll
  for (int a = 0; a < 4; ++a)
#pragma unroll
    for (int r = 0; r < 4; ++r) {
      int v = v0 + a * 16 + lq * 4 + r;
      if (v < 513) {
#pragma unroll
        for (int n = 0; n < 2; ++n) {
          float re = cre[a][n][r], im = cim[a][n][r];
          float wf = gainw(re, im, alpha, a1);
          outp[(size_t)v * 1024 + n * 16 + lm] =
              __float22half2_rn(make_float2(re * wf, im * wf));
        }
      }
    }
}

// ------------------------------------------------- k4m: MFMA inverse u-FFT (in place)
// [round-15 version, proven]
__global__ __launch_bounds__(256) void k4_invfft(__half2* __restrict__ Ct, int nrows)
{
  __shared__ unsigned short CM[4][32][TP];      // CreHi, CreLo, CimHi, CimLo
  __shared__ unsigned short SC[4][4][32][TP];   // [wave][Mre, MimNeg, Ttre, TtimNeg]
  const int tid = threadIdx.x;
  const int lane = tid & 63, w = tid >> 6;
  const int lm = lane & 15, lq = lane >> 4;

  // build constants: [r][c] = W32^(br5(c)*r), W32 = e^{+2pi i/32}
  for (int i = tid; i < 1024; i += 256) {
    int r = i >> 5, c = i & 31;
    int brc = ((c & 1) << 4) | ((c & 2) << 2) | (c & 4) | ((c & 8) >> 2) | ((c & 16) >> 4);
    float ang = (float)((brc * r) & 31) * 0.19634954084936207f;  // 2pi/32
    float sv, cv;
    __sincosf(ang, &sv, &cv);
    __half chh = __float2half(cv), shh = __float2half(sv);
    CM[0][r][c] = __half_as_ushort(chh);
    CM[1][r][c] = __half_as_ushort(__float2half(cv - __half2float(chh)));
    CM[2][r][c] = __half_as_ushort(shh);
    CM[3][r][c] = __half_as_ushort(__float2half(sv - __half2float(shh)));
  }
  __syncthreads();

  half8 cf[4][2];
#pragma unroll
  for (int cmp = 0; cmp < 4; ++cmp)
#pragma unroll
    for (int t = 0; t < 2; ++t)
      cf[cmp][t] = *(const half8*)&CM[cmp][t * 16 + lm][lq * 8];

  unsigned short (*MRE)[TP] = SC[w][0];
  unsigned short (*MIM)[TP] = SC[w][1];  // holds -Im
  unsigned short (*TRE)[TP] = SC[w][2];
  unsigned short (*TIM)[TP] = SC[w][3];  // holds -Im

  const int slot = blockIdx.x * 4 + w;
  __half2* __restrict__ plane = Ct + (size_t)blockIdx.y * 513 * 1024;

#pragma unroll 1
  for (int rr = 0; rr < 4; ++rr) {
    const int vrow = slot * 4 + rr;
    const bool act = (vrow < nrows);
    __half2* __restrict__ row = plane + ((size_t)(act ? vrow : 0) << 10);
    int4 ch4[4];
#pragma unroll
    for (int k = 0; k < 4; ++k)
      ch4[k] = act ? *(const int4*)&row[4 * (lane + 64 * k)] : make_int4(0, 0, 0, 0);
#pragma unroll
    for (int k = 0; k < 4; ++k) {
      const unsigned* e = (const unsigned*)&ch4[k];
      unsigned short re4[4], im4[4];
#pragma unroll
      for (int j = 0; j < 4; ++j) {
        unsigned u = e[j];
        re4[j] = (unsigned short)(u & 0xFFFFu);
        im4[j] = (unsigned short)((u >> 16) ^ 0x8000u);  // negated im
      }
      int h = (lane >> 3) + 8 * k, c0 = 4 * (lane & 7);
      *(int2*)&MRE[h][c0] = *(int2*)re4;
      *(int2*)&MIM[h][c0] = *(int2*)im4;
    }
    __syncthreads();  // B1: M staged

    half8 mre[2], mng[2], mps[2];
#pragma unroll
    for (int t = 0; t < 2; ++t) {
      mre[t] = *(const half8*)&MRE[t * 16 + lm][lq * 8];
      mng[t] = *(const half8*)&MIM[t * 16 + lm][lq * 8];
      mps[t] = hneg(mng[t]);
    }
    f32x4 ar[2][2] = {}, ai[2][2] = {};
#pragma unroll
    for (int i = 0; i < 2; ++i)
#pragma unroll
      for (int j = 0; j < 2; ++j) {
        ar[i][j] = __builtin_amdgcn_mfma_f32_16x16x32_f16(mre[i], cf[0][j], ar[i][j], 0, 0, 0);
        ar[i][j] = __builtin_amdgcn_mfma_f32_16x16x32_f16(mre[i], cf[1][j], ar[i][j], 0, 0, 0);
        ar[i][j] = __builtin_amdgcn_mfma_f32_16x16x32_f16(mng[i], cf[2][j], ar[i][j], 0, 0, 0);
        ar[i][j] = __builtin_amdgcn_mfma_f32_16x16x32_f16(mng[i], cf[3][j], ar[i][j], 0, 0, 0);
        ai[i][j] = __builtin_amdgcn_mfma_f32_16x16x32_f16(mre[i], cf[2][j], ai[i][j], 0, 0, 0);
        ai[i][j] = __builtin_amdgcn_mfma_f32_16x16x32_f16(mre[i], cf[3][j], ai[i][j], 0, 0, 0);
        ai[i][j] = __builtin_amdgcn_mfma_f32_16x16x32_f16(mps[i], cf[0][j], ai[i][j], 0, 0, 0);
        ai[i][j] = __builtin_amdgcn_mfma_f32_16x16x32_f16(mps[i], cf[1][j], ai[i][j], 0, 0, 0);
      }

#pragma unroll
    for (int i = 0; i < 2; ++i)
#pragma unroll
      for (int j = 0; j < 2; ++j) {
        unsigned short tr4[4], ti4[4];
#pragma unroll
        for (int r = 0; r < 4; ++r) {
          int h = i * 16 + lq * 4 + r;
          int q0 = j * 16 + lm;
          int brh = ((h & 1) << 4) | ((h & 2) << 2) | (h & 4) | ((h & 8) >> 2) | ((h & 16) >> 4);
          float ang = (float)(brh * q0) * 0.006135923151542565f;  // 2pi/1024
          float sv, cv;
          __sincosf(ang, &sv, &cv);
          float nre = ar[i][j][r], nim = ai[i][j][r];
          float tre = cv * nre - sv * nim;
          float tim = cv * nim + sv * nre;
          tr4[r] = __half_as_ushort(__float2half(tre));
          ti4[r] = __half_as_ushort(__float2half(-tim));
        }
        *(int2*)&TRE[j * 16 + lm][i * 16 + lq * 4] = *(int2*)tr4;
        *(int2*)&TIM[j * 16 + lm][i * 16 + lq * 4] = *(int2*)ti4;
      }
    __syncthreads();  // B2: T staged

    half8 tre[2], tng[2], tps[2];
#pragma unroll
    for (int t = 0; t < 2; ++t) {
      tre[t] = *(const half8*)&TRE[t * 16 + lm][lq * 8];
      tng[t] = *(const half8*)&TIM[t * 16 + lm][lq * 8];
      tps[t] = hneg(tng[t]);
    }
    f32x4 gr[2][2] = {}, gi[2][2] = {};
#pragma unroll
    for (int i = 0; i < 2; ++i)
#pragma unroll
      for (int j = 0; j < 2; ++j) {
        gr[i][j] = __builtin_amdgcn_mfma_f32_16x16x32_f16(cf[0][i], tre[j], gr[i][j], 0, 0, 0);
        gr[i][j] = __builtin_amdgcn_mfma_f32_16x16x32_f16(cf[1][i], tre[j], gr[i][j], 0, 0, 0);
        gr[i][j] = __builtin_amdgcn_mfma_f32_16x16x32_f16(cf[2][i], tng[j], gr[i][j], 0, 0, 0);
        gr[i][j] = __builtin_amdgcn_mfma_f32_16x16x32_f16(cf[3][i], tng[j], gr[i][j], 0, 0, 0);
        gi[i][j] = __builtin_amdgcn_mfma_f32_16x16x32_f16(cf[0][i], tps[j], gi[i][j], 0, 0, 0);
        gi[i][j] = __builtin_amdgcn_mfma_f32_16x16x32_f16(cf[1][i], tps[j], gi[i][j], 0, 0, 0);
        gi[i][j] = __builtin_amdgcn_mfma_f32_16x16x32_f16(cf[2][i], tre[j], gi[i][j], 0, 0, 0);
        gi[i][j] = __builtin_amdgcn_mfma_f32_16x16x32_f16(cf[3][i], tre[j], gi[i][j], 0, 0, 0);
      }

    if (act) {
#pragma unroll
      for (int i = 0; i < 2; ++i)
#pragma unroll
        for (int j = 0; j < 2; ++j)
#pragma unroll
          for (int r = 0; r < 4; ++r) {
            int q = 512 * i + 128 * lq + 32 * r + 16 * j + lm;
            row[q] = __float22half2_rn(make_float2(gr[i][j][r], gi[i][j][r]));
          }
    }
  }
}

// ------------------------------------------------- k56m: MFMA inverse row FFT + softmax + PV
// 512 thr / 8 waves; wave w owns complex row p = w (G rows 2w, 2w+1).
// S[k0+32k1] = sum_v0 D[k1][v0] * (W^{+v0 k0} * sum_v1 M[v0][v1] D[k0][v1]),
// D[r][c] = W32^{+rc} (hi/lo split). Per-wave scratch SA/SB (M -> T -> ST).
// Output ST tile gives lane l the contiguous k-block [16l, 16l+16) -> P as
// 2x b128/row. LDS: GP [0,34816) Gbuf(2064)/P(2080)/red(68f) overlay +
// scratch [34816, 75776).
__global__ __launch_bounds__(512) void k56_softmax_av(
    const __half2* __restrict__ Ct, const short* __restrict__ Vt,
    short* __restrict__ ctx, int bh0)
{
  __shared__ __align__(16) char GP[75776];
  const int tid = threadIdx.x;
  const int q0 = blockIdx.x * 16, z = blockIdx.y;
  const int lane = tid & 63, w = tid >> 6;  // w = 0..7
  const int lm = lane & 15, lq = lane >> 4;

  // ---- phase 0: constants D in GP[0,10240) (overwritten by staging later)
  {
    unsigned short* CMf = (unsigned short*)GP;  // [4][32][TP]
    for (int i = tid; i < 1024; i += 512) {
      int r = i >> 5, c = i & 31;
      float ang = (float)((r * c) & 31) * 0.19634954084936207f;  // 2pi/32
      float sv, cv;
      __sincosf(ang, &sv, &cv);
      __half chh = __float2half(cv), shh = __float2half(sv);
      CMf[0 * 32 * TP + r * TP + c] = __half_as_ushort(chh);
      CMf[1 * 32 * TP + r * TP + c] = __half_as_ushort(__float2half(cv - __half2float(chh)));
      CMf[2 * 32 * TP + r * TP + c] = __half_as_ushort(shh);
      CMf[3 * 32 * TP + r * TP + c] = __half_as_ushort(__float2half(sv - __half2float(shh)));
    }
  }
  __syncthreads();
  half8 cf[4][2];
#pragma unroll
  for (int cmp = 0; cmp < 4; ++cmp)
#pragma unroll
    for (int t = 0; t < 2; ++t)
      cf[cmp][t] = *(const half8*)&((unsigned short*)GP)[cmp * 32 * TP + (t * 16 + lm) * TP + lq * 8];
  __syncthreads();  // cf loaded; GP[0,*) free for Gbuf

  // ---- phase 1: stage Gbuf (pitch 2064 B, rows 0..15)
  const __half2* __restrict__ in = Ct + (size_t)z * 513 * 1024;
#define GROW(m) ((__half2*)(GP + (m) * 2064))
  for (int id = tid; id < 2052; id += 512) {
    int v = id >> 2, qq = (id & 3) * 4;
    int4 o = *(const int4*)&in[(size_t)v * 1024 + q0 + qq];
    __half2* op = (__half2*)&o;
#pragma unroll
    for (int i = 0; i < 4; ++i) GROW(qq + i)[v] = op[i];
  }
  __syncthreads();  // Gbuf ready

  // ---- phase 2: gather z -> M scratch (wave-private)
  unsigned short (*SA)[TP] = (unsigned short (*)[TP])(GP + 34816 + w * 5120);
  unsigned short (*SB)[TP] = (unsigned short (*)[TP])(GP + 34816 + w * 5120 + 2560);
  {
    const __half2* g1 = GROW(2 * w);
    const __half2* g2 = GROW(2 * w + 1);
    const int v0 = lane & 31;
    const int v1b = (lane >> 5) * 16;
    unsigned short re16[16], im16[16];
#pragma unroll
    for (int jj = 0; jj < 16; ++jj) {
      int v = v0 + 32 * (v1b + jj);
      float2 a, b;
      if (v <= 512) {
        a = __half22float2(g1[v]);
        b = __half22float2(g2[v]);
      } else {
        int v2 = 1024 - v;
        float2 aa = __half22float2(g1[v2]), bb = __half22float2(g2[v2]);
        a = make_float2(aa.x, -aa.y);
        b = make_float2(bb.x, -bb.y);
      }
      float zre = a.x - b.y, zim = a.y + b.x;
      re16[jj] = __half_as_ushort(__float2half(zre));
      im16[jj] = __half_as_ushort(__float2half(-zim));  // store -Im
    }
    *(short8*)&SA[v0][v1b]     = *(short8*)&re16[0];
    *(short8*)&SA[v0][v1b + 8] = *(short8*)&re16[8];
    *(short8*)&SB[v0][v1b]     = *(short8*)&im16[0];
    *(short8*)&SB[v0][v1b + 8] = *(short8*)&im16[8];
  }
  __syncthreads();  // ALL gathers done: Gbuf dead, P region writable

  // ---- phase 3: stage-1 matmul  T[v0][k0] = sum_v1 M[v0][v1] D[k0][v1]
  half8 mre[2], mng[2], mps[2];
#pragma unroll
  for (int t = 0; t < 2; ++t) {
    mre[t] = *(const half8*)&SA[t * 16 + lm][lq * 8];
    mng[t] = *(const half8*)&SB[t * 16 + lm][lq * 8];
    mps[t] = hneg(mng[t]);
  }
  f32x4 ar[2][2] = {}, ai[2][2] = {};
#pragma unroll
  for (int i = 0; i < 2; ++i)
#pragma unroll
    for (int j = 0; j < 2; ++j) {
      ar[i][j] = __builtin_amdgcn_mfma_f32_16x16x32_f16(mre[i], cf[0][j], ar[i][j], 0, 0, 0);
      ar[i][j] = __builtin_amdgcn_mfma_f32_16x16x32_f16(mre[i], cf[1][j], ar[i][j], 0, 0, 0);
      ar[i][j] = __builtin_amdgcn_mfma_f32_16x16x32_f16(mng[i], cf[2][j], ar[i][j], 0, 0, 0);
      ar[i][j] = __builtin_amdgcn_mfma_f32_16x16x32_f16(mng[i], cf[3][j], ar[i][j], 0, 0, 0);
      ai[i][j] = __builtin_amdgcn_mfma_f32_16x16x32_f16(mre[i], cf[2][j], ai[i][j], 0, 0, 0);
      ai[i][j] = __builtin_amdgcn_mfma_f32_16x16x32_f16(mre[i], cf[3][j], ai[i][j], 0, 0, 0);
      ai[i][j] = __builtin_amdgcn_mfma_f32_16x16x32_f16(mps[i], cf[0][j], ai[i][j], 0, 0, 0);
      ai[i][j] = __builtin_amdgcn_mfma_f32_16x16x32_f16(mps[i], cf[1][j], ai[i][j], 0, 0, 0);
    }

  // twiddle W^{+v0 k0}; transposed store T^T[k0][v0] into SA/SB (wave-private
  // reuse: M fragment reads above complete before these writes in-order)
#pragma unroll
  for (int i = 0; i < 2; ++i)
#pragma unroll
    for (int j = 0; j < 2; ++j) {
      unsigned short tr4[4], ti4[4];
#pragma unroll
      for (int r = 0; r < 4; ++r) {
        int v0 = i * 16 + lq * 4 + r;
        int k0 = j * 16 + lm;
        float ang = (float)(v0 * k0) * 0.006135923151542565f;  // 2pi/1024
        float sv, cv;
        __sincosf(ang, &sv, &cv);
        float nre = ar[i][j][r], nim = ai[i][j][r];
        tr4[r] = __half_as_ushort(__float2half(cv * nre - sv * nim));
        ti4[r] = __half_as_ushort(__float2half(-(cv * nim + sv * nre)));
      }
      *(int2*)&SA[j * 16 + lm][i * 16 + lq * 4] = *(int2*)tr4;
      *(int2*)&SB[j * 16 + lm][i * 16 + lq * 4] = *(int2*)ti4;
    }

  // ---- phase 4: stage-2 matmul  S[k1][k0] = sum_v0 D[k1][v0] T'[v0][k0]
  half8 tre[2], tng[2], tps[2];
#pragma unroll
  for (int t = 0; t < 2; ++t) {
    tre[t] = *(const half8*)&SA[t * 16 + lm][lq * 8];
    tng[t] = *(const half8*)&SB[t * 16 + lm][lq * 8];
    tps[t] = hneg(tng[t]);
  }
  f32x4 gr[2][2] = {}, gi[2][2] = {};
#pragma unroll
  for (int i = 0; i < 2; ++i)
#pragma unroll
    for (int j = 0; j < 2; ++j) {
      gr[i][j] = __builtin_amdgcn_mfma_f32_16x16x32_f16(cf[0][i], tre[j], gr[i][j], 0, 0, 0);
      gr[i][j] = __builtin_amdgcn_mfma_f32_16x16x32_f16(cf[1][i], tre[j], gr[i][j], 0, 0, 0);
      gr[i][j] = __builtin_amdgcn_mfma_f32_16x16x32_f16(cf[2][i], tng[j], gr[i][j], 0, 0, 0);
      gr[i][j] = __builtin_amdgcn_mfma_f32_16x16x32_f16(cf[3][i], tng[j], gr[i][j], 0, 0, 0);
      gi[i][j] = __builtin_amdgcn_mfma_f32_16x16x32_f16(cf[0][i], tps[j], gi[i][j], 0, 0, 0);
      gi[i][j] = __builtin_amdgcn_mfma_f32_16x16x32_f16(cf[1][i], tps[j], gi[i][j], 0, 0, 0);
      gi[i][j] = __builtin_amdgcn_mfma_f32_16x16x32_f16(cf[2][i], tre[j], gi[i][j], 0, 0, 0);
      gi[i][j] = __builtin_amdgcn_mfma_f32_16x16x32_f16(cf[3][i], tre[j], gi[i][j], 0, 0, 0);
    }

  // ---- phase 5: wave-local softmax on fragments
  float m1 = -3.4e38f, m2 = -3.4e38f;
#pragma unroll
  for (int i = 0; i < 2; ++i)
#pragma unroll
    for (int j = 0; j < 2; ++j)
#pragma unroll
      for (int r = 0; r < 4; ++r) {
        m1 = fmaxf(m1, gr[i][j][r]);
        m2 = fmaxf(m2, gi[i][j][r]);
      }
#pragma unroll
  for (int s = 32; s > 0; s >>= 1) {
    m1 = fmaxf(m1, __shfl_xor(m1, s, 64));
    m2 = fmaxf(m2, __shfl_xor(m2, s, 64));
  }
  float s1 = 0.f, s2 = 0.f;
#pragma unroll
  for (int i = 0; i < 2; ++i)
#pragma unroll
    for (int j = 0; j < 2; ++j)
#pragma unroll
      for (int r = 0; r < 4; ++r) {
        float e1 = __expf(gr[i][j][r] - m1);
        float e2 = __expf(gi[i][j][r] - m2);
        gr[i][j][r] = e1;
        gi[i][j][r] = e2;
        s1 += e1;
        s2 += e2;
      }
#pragma unroll
  for (int s = 32; s > 0; s >>= 1) {
    s1 += __shfl_xor(s1, s, 64);
    s2 += __shfl_xor(s2, s, 64);
  }
  float inv1 = 1.0f / s1, inv2 = 1.0f / s2;

  // ---- phase 6: ST transpose tiles (SA=re, SB=im; T reads done) -> P rows
  short* P = (short*)GP;  // row m at m*1040 shorts
#pragma unroll
  for (int i = 0; i < 2; ++i)
#pragma unroll
    for (int j = 0; j < 2; ++j)
#pragma unroll
      for (int r = 0; r < 4; ++r) {
        SA[i * 16 + lq * 4 + r][j * 16 + lm] = (unsigned short)f2bf(gr[i][j][r] * inv1);
        SB[i * 16 + lq * 4 + r][j * 16 + lm] = (unsigned short)f2bf(gi[i][j][r] * inv2);
      }
  {
    int rowk = lane >> 1, colb = 16 * (lane & 1);
    short8 a0 = *(short8*)&SA[rowk][colb];
    short8 a1 = *(short8*)&SA[rowk][colb + 8];
    short8 b0 = *(short8*)&SB[rowk][colb];
    short8 b1 = *(short8*)&SB[rowk][colb + 8];
    short* dst0 = &P[(2 * w) * 1040 + 16 * lane];
    short* dst1 = &P[(2 * w + 1) * 1040 + 16 * lane];
    *(short8*)dst0       = a0;
    *(short8*)(dst0 + 8) = a1;
    *(short8*)dst1       = b0;
    *(short8*)(dst1 + 8) = b1;
  }
  __syncthreads();  // P complete

  // ---- phase 7: PV (unchanged): wave w covers k in [w*128, w*128+128)
  const short* __restrict__ Vp = Vt + ((size_t)(bh0 + z) << 16);
  f32x4 acc[4] = {};
#pragma unroll
  for (int ks = 0; ks < 4; ++ks) {
    int k0 = w * 128 + ks * 32;
    short8 a0 = *(const short8*)&P[lm * 1040 + k0 + lq * 8];
#pragma unroll
    for (int b = 0; b < 4; ++b) {
      short8 bv = *(const short8*)&Vp[(size_t)(b * 16 + lm) * 1024 + k0 + lq * 8];
      acc[b] = __builtin_amdgcn_mfma_f32_16x16x32_bf16(a0, bv, acc[b], 0, 0, 0);
    }
  }
  __syncthreads();  // all P reads done; reuse GP for reduction
  float* red = (float*)GP;  // pitch 68 floats (conflict-free); 128*68*4 = 34816 B
#pragma unroll
  for (int b = 0; b < 4; ++b)
#pragma unroll
    for (int r = 0; r < 4; ++r)
      red[(w * 16 + lq * 4 + r) * 68 + b * 16 + lm] = acc[b][r];
  __syncthreads();
  if (tid < 256) {
    int q = tid >> 4, d0 = (tid & 15) * 4;
    float s0 = 0.f, s1_ = 0.f, s2_ = 0.f, s3 = 0.f;
#pragma unroll
    for (int ww = 0; ww < 8; ++ww) {
      const float* rr = &red[(ww * 16 + q) * 68 + d0];
      s0 += rr[0]; s1_ += rr[1]; s2_ += rr[2]; s3 += rr[3];
    }
    short o4[4] = {f2bf(s0), f2bf(s1_), f2bf(s2_), f2bf(s3)};
    *(int2*)&ctx[(((size_t)(bh0 + z)) << 16) + (size_t)(q0 + q) * 64 + d0] = *(int2*)o4;
  }
#undef GROW
}

// ------------------------------------------------- k7: out = ctx @ Wo^T + bo (XCD-swizzled)
__global__ __launch_bounds__(256) void k7_out(
    const short* __restrict__ ctx, const void* __restrict__ Wo,
    const void* __restrict__ bo, void* __restrict__ out,
    const int* __restrict__ flags)
{
  __shared__ __align__(16) char smem[128 * 136 * 2];
  short* As = (short*)smem;
  short* Bs = As + 128 * PITCH;
  short* Ct = (short*)smem;
  const int isf32 = flags[0];
  const int t = threadIdx.x;
  const int lb = blockIdx.x;
  const int m0 = ((lb & 7) * 4 + ((lb >> 3) & 3)) * 128;
  const int n0 = (lb >> 5) * 128;
  const int lane = t & 63, wvi = t >> 6;
  const int wr = wvi >> 1, wc = wvi & 1;
  const int lm = lane & 15, lq = lane >> 4;
  f32x4 acc[4][4] = {};

  for (int k0 = 0; k0 < 1024; k0 += 32) {
    __syncthreads();
#pragma unroll
    for (int i = 0; i < 2; ++i) {
      int l = t + i * 256;
      int row = l >> 2, kk = (l & 3) << 3;
      int n = m0 + row, e = k0 + kk;
      size_t aaddr = (((size_t)((n >> 10) * 16 + (e >> 6))) << 16) + (size_t)((n & 1023) << 6) + (e & 63);
      *(int4*)&As[row * PITCH + kk] = *(const int4*)&ctx[aaddr];
      *(short8*)&Bs[row * PITCH + kk] = ld8(Wo, (size_t)(n0 + row) * 1024 + e, isf32);
    }
    __syncthreads();
    short8 af[4], bf[4];
#pragma unroll
    for (int a = 0; a < 4; ++a) af[a] = *(const short8*)&As[(wr * 64 + a * 16 + lm) * PITCH + lq * 8];
#pragma unroll
    for (int b = 0; b < 4; ++b) bf[b] = *(const short8*)&Bs[(wc * 64 + b * 16 + lm) * PITCH + lq * 8];
#pragma unroll
    for (int a = 0; a < 4; ++a)
#pragma unroll
      for (int b = 0; b < 4; ++b)
        acc[a][b] = __builtin_amdgcn_mfma_f32_16x16x32_bf16(af[a], bf[b], acc[a][b], 0, 0, 0);
  }

  if (isf32) {
#pragma unroll
    for (int a = 0; a < 4; ++a)
#pragma unroll
      for (int b = 0; b < 4; ++b) {
        int col = n0 + wc * 64 + b * 16 + lm;
        float bo_ = ldf(bo, col, 1);
#pragma unroll
        for (int r = 0; r < 4; ++r) {
          int row = m0 + wr * 64 + a * 16 + lq * 4 + r;
          ((float*)out)[(size_t)row * 1024 + col] = acc[a][b][r] + bo_;
        }
      }
    return;
  }
  __syncthreads();
#pragma unroll
  for (int a = 0; a < 4; ++a)
#pragma unroll
    for (int b = 0; b < 4; ++b) {
      int col = wc * 64 + b * 16 + lm;
      float bo_ = ldf(bo, n0 + col, 0);
#pragma unroll
      for (int r = 0; r < 4; ++r) {
        int row = wr * 64 + a * 16 + lq * 4 + r;
        Ct[row * 136 + col] = f2bf(acc[a][b][r] + bo_);
      }
    }
  __syncthreads();
#pragma unroll
  for (int j = 0; j < 8; ++j) {
    int id = t + j * 256;
    int row = id >> 4, c16 = (id & 15) * 8;
    short8 v = *(const short8*)&Ct[row * 136 + c16];
    *(short8*)&((short*)out)[(size_t)(m0 + row) * 1024 + n0 + c16] = v;
  }
}

// ------------------------------------------------- launch
extern "C" void kernel_launch(void* const* d_in, const int* in_sizes, int n_in,
                              void* d_out, int out_size, void* d_ws, size_t ws_size,
                              hipStream_t stream)
{
  const void* x  = d_in[0];
  const void* Wq = d_in[1];
  const void* bq = d_in[2];
  const void* Wk = d_in[3];
  const void* bk = d_in[4];
  const void* Wv = d_in[5];
  const void* bv = d_in[6];
  const void* Wo = d_in[7];
  const void* bo = d_in[8];
  const void* alphap = d_in[9];
  char* ws = (char*)d_ws;

  const size_t PLANE_CT = (size_t)513 * 1024 * 4;  // 2,101,248 B
  const size_t QH_SZ = (size_t)64 * 64 * 1024 * 4; // 16 MiB
  const size_t KH_SZ = (size_t)64 * 64 * 520 * 4;  // 8.125 MiB

  // ---- big path layout: Ct-all overlays Qt/Kt ----
  const size_t B_CT  = 0;
  const size_t B_VT  = 64 * PLANE_CT;            // 134,479,872
  const size_t B_CX  = B_VT + ((size_t)8u << 20);
  const size_t B_QH  = B_CX + ((size_t)8u << 20);
  const size_t B_KH  = B_QH + QH_SZ;
  const size_t B_FL  = B_KH + KH_SZ;
  const size_t B_NEED = B_FL + 256;

  if (ws_size >= B_NEED) {
    short*   Qt   = (short*)(ws);
    short*   Kt   = (short*)(ws + ((size_t)8u << 20));
    short*   Vt   = (short*)(ws + B_VT);
    short*   ctx  = (short*)(ws + B_CX);
    __half2* Ct   = (__half2*)(ws + B_CT);   // overlays Qt/Kt (dead after kA)
    __half2* Qhat = (__half2*)(ws + B_QH);
    __half2* Khat = (__half2*)(ws + B_KH);
    int*     flags = (int*)(ws + B_FL);

    k0_detect<<<1, 256, 0, stream>>>((const unsigned*)x, alphap, flags);
    k1_qkv<<<dim3(256, 3), 256, 0, stream>>>(x, Wq, bq, Wk, bk, Wv, bv, Qt, Kt, Vt, flags);
    kA_qkfft<<<dim3(32, 64), 128, 0, stream>>>(Qt, Kt, Qhat, Khat);
    kB_specmm<<<dim3(8, 9, 64), 256, 0, stream>>>(Qhat, Khat, Ct, flags, 0);
    k4_invfft<<<dim3(33, 64), 256, 0, stream>>>(Ct, 513);
    k56_softmax_av<<<dim3(64, 64), 512, 0, stream>>>(Ct, Vt, ctx, 0);
    k7_out<<<256, 256, 0, stream>>>(ctx, Wo, bo, d_out, flags);
    return;
  }

  // ---- chunked fallback (proven ~59.9 MiB layout) ----
  const size_t VT_OFF = (size_t)17u << 20;
  const size_t CX_OFF = (size_t)25u << 20;
  const size_t QH_OFF = (size_t)33u << 20;
  const size_t KH_OFF = QH_OFF + QH_SZ;
  const size_t FL_OFF = KH_OFF + KH_SZ;

  short*   Qt   = (short*)(ws);
  short*   Kt   = (short*)(ws + ((size_t)8u << 20));
  short*   Vt   = (short*)(ws + VT_OFF);
  short*   ctx  = (short*)(ws + CX_OFF);
  __half2* Ct   = (__half2*)(ws);          // overlays Qt/Kt (dead after kA)
  __half2* Qhat = (__half2*)(ws + QH_OFF);
  __half2* Khat = (__half2*)(ws + KH_OFF);
  int*     flags = (int*)(ws + FL_OFF);

  k0_detect<<<1, 256, 0, stream>>>((const unsigned*)x, alphap, flags);
  k1_qkv<<<dim3(256, 3), 256, 0, stream>>>(x, Wq, bq, Wk, bk, Wv, bv, Qt, Kt, Vt, flags);
  kA_qkfft<<<dim3(32, 64), 128, 0, stream>>>(Qt, Kt, Qhat, Khat);
  for (int c = 0; c < 8; ++c) {
    int bh0 = c * 8;
    kB_specmm<<<dim3(8, 9, 8), 256, 0, stream>>>(Qhat, Khat, Ct, flags, bh0);
    k4_invfft<<<dim3(33, 8), 256, 0, stream>>>(Ct, 513);
    k56_softmax_av<<<dim3(64, 8), 512, 0, stream>>>(Ct, Vt, ctx, bh0);
  }
  k7_out<<<256, 256, 0, stream>>>(ctx, Wo, bo, d_out, flags);
}